// Round 6
// baseline (16095.227 us; speedup 1.0000x reference)
//
#include <hip/hip_runtime.h>
#include <math.h>

// ---------------------------------------------------------------------------
// AE_control: B=1024, T=512, D=64, K=9, NUM_M=64, NUM_N=32, SCALE=1
// Outputs (flat f32): s_hat[512K], n_hat[512K], idx_s[512K], idx_n[512K]
// Encoder + argmin in f64 (idx needs exact argmin vs f64 np reference).
// Decoder + FC in f32. FC = per-chunk split-K SGEMM.
// R6: conv64/conv32 restructured to 32 couts/wave (2x FMA per lgkm event).
// ---------------------------------------------------------------------------

#define TB 512
#define BATCH 1024

// (nmat, C, C, 9) f32 -> (nmat, 9, C, C) f64  [k][cin][cout]
__global__ __launch_bounds__(256) void transpose_w_f64_kernel(
    const float* __restrict__ w, double* __restrict__ wT, int C, int nmat) {
  int total = nmat * C * C * 9;
  for (int i = blockIdx.x * blockDim.x + threadIdx.x; i < total;
       i += gridDim.x * blockDim.x) {
    int mat = i / (C * C * 9);
    int r = i % (C * C * 9);
    int cout = r / (C * 9);
    int rem = r % (C * 9);
    int cin = rem / 9;
    int k = rem % 9;
    wT[mat * C * C * 9 + (k * C + cin) * C + cout] = (double)w[i];
  }
}

// (nmat, C, C, 9) f32 -> (nmat, 9, C, C) f32
__global__ __launch_bounds__(256) void transpose_w_f32_kernel(
    const float* __restrict__ w, float* __restrict__ wT, int C, int nmat) {
  int total = nmat * C * C * 9;
  for (int i = blockIdx.x * blockDim.x + threadIdx.x; i < total;
       i += gridDim.x * blockDim.x) {
    int mat = i / (C * C * 9);
    int r = i % (C * C * 9);
    int cout = r / (C * 9);
    int rem = r % (C * 9);
    int cin = rem / 9;
    int k = rem % 9;
    wT[mat * C * C * 9 + (k * C + cin) * C + cout] = w[i];
  }
}

// enc0 fused block (f64): x f32 (BC,512) -> out f64 (BC,64,512)
__global__ __launch_bounds__(256) void enc0_f64_kernel(
    const float* __restrict__ x, const float* __restrict__ w1,
    const float* __restrict__ b1, const double* __restrict__ w2T,
    const float* __restrict__ b2, const float* __restrict__ wsc,
    const float* __restrict__ bsc, double* __restrict__ out) {
  __shared__ double xs[80];
  __shared__ double w1s[576];
  __shared__ double b1s[64];
  __shared__ double mid[64 * 72];
  int b = blockIdx.y;
  int t0 = blockIdx.x * 64;
  int tid = threadIdx.x;
  if (tid < 80) {
    int t = t0 - 8 + tid;
    xs[tid] = (t >= 0 && t < TB) ? (double)x[b * TB + t] : 0.0;
  }
  for (int i = tid; i < 576; i += 256) w1s[i] = (double)w1[i];
  if (tid < 64) b1s[tid] = (double)b1[tid];
  __syncthreads();
  for (int e = tid; e < 64 * 72; e += 256) {
    int cout = e / 72, tt = e % 72;
    int t = t0 - 4 + tt;
    double acc = b1s[cout];
#pragma unroll
    for (int k = 0; k < 9; ++k) acc = fma(w1s[cout * 9 + k], xs[tt + k], acc);
    mid[e] = (t >= 0 && t < TB) ? fmax(acc, 0.0) : 0.0;
  }
  __syncthreads();
  int wave = __builtin_amdgcn_readfirstlane(tid >> 6);
  int lane = tid & 63;
  int cbase = wave * 16;
  double acc[16];
#pragma unroll
  for (int j = 0; j < 16; ++j) acc[j] = (double)b2[cbase + j];
  for (int cin = 0; cin < 64; ++cin) {
#pragma unroll
    for (int k = 0; k < 9; ++k) {
      double xv = mid[cin * 72 + lane + k];
      const double* wp = w2T + (k * 64 + cin) * 64 + cbase;
#pragma unroll
      for (int j = 0; j < 16; ++j) acc[j] = fma(xv, wp[j], acc[j]);
    }
  }
  double xc = xs[8 + lane];
#pragma unroll
  for (int j = 0; j < 16; ++j) {
    double v = acc[j] + fma((double)wsc[cbase + j], xc, (double)bsc[cbase + j]);
    out[(b * 64 + cbase + j) * TB + t0 + lane] = fmax(v, 0.0);
  }
}

// f64 conv 64->64, K=9, SAME: 128 thr = 2 waves, each wave 32 couts x 64 t.
// 32 f64 FMA (128 issue-cycles) per ds_read_b64 + 256B scalar weights.
template <bool SKIP>
__global__ __launch_bounds__(128) void conv64_f64_kernel(
    const double* __restrict__ in, const double* __restrict__ wT,
    const float* __restrict__ bias, const double* __restrict__ skip,
    double* __restrict__ out) {
  __shared__ double xs[64 * 72];
  int b = blockIdx.y;
  int t0 = blockIdx.x * 64;
  int tid = threadIdx.x;
  for (int i = tid; i < 64 * 72; i += 128) {
    int cin = i / 72, tt = i % 72;
    int t = t0 - 4 + tt;
    xs[i] = (t >= 0 && t < TB) ? in[(b * 64 + cin) * TB + t] : 0.0;
  }
  __syncthreads();
  int wave = __builtin_amdgcn_readfirstlane(tid >> 6);
  int lane = tid & 63;
  int cbase = wave * 32;
  double acc[32];
#pragma unroll
  for (int j = 0; j < 32; ++j) acc[j] = (double)bias[cbase + j];
  for (int cin = 0; cin < 64; ++cin) {
#pragma unroll
    for (int k = 0; k < 9; ++k) {
      double xv = xs[cin * 72 + lane + k];
      const double* wp = wT + (k * 64 + cin) * 64 + cbase;
#pragma unroll
      for (int j = 0; j < 32; ++j) acc[j] = fma(xv, wp[j], acc[j]);
    }
  }
  int t = t0 + lane;
#pragma unroll
  for (int j = 0; j < 32; ++j) {
    double v = acc[j];
    if constexpr (SKIP) v += skip[(b * 64 + cbase + j) * TB + t];
    out[(b * 64 + cbase + j) * TB + t] = fmax(v, 0.0);
  }
}

// f32 conv 32->32 (decoder): 128 thr = 2 waves; wave w -> t-half, all 32 couts.
template <bool SKIP>
__global__ __launch_bounds__(128) void conv32_f32_kernel(
    const float* __restrict__ in, const float* __restrict__ wT,
    const float* __restrict__ bias, const float* __restrict__ skip,
    float* __restrict__ out) {
  constexpr int XW = 136;
  __shared__ float xs[32 * XW];
  int b = blockIdx.y;
  int t0 = blockIdx.x * 128;
  int tid = threadIdx.x;
  for (int i = tid; i < 32 * XW; i += 128) {
    int cin = i / XW, tt = i % XW;
    int t = t0 - 4 + tt;
    xs[i] = (t >= 0 && t < TB) ? in[(b * 32 + cin) * TB + t] : 0.f;
  }
  __syncthreads();
  int wave = __builtin_amdgcn_readfirstlane(tid >> 6);
  int lane = tid & 63;
  int ttl = wave * 64 + lane;
  float acc[32];
#pragma unroll
  for (int j = 0; j < 32; ++j) acc[j] = bias[j];
  for (int cin = 0; cin < 32; ++cin) {
#pragma unroll
    for (int k = 0; k < 9; ++k) {
      float xv = xs[cin * XW + ttl + k];
      const float* wp = wT + (k * 32 + cin) * 32;
#pragma unroll
      for (int j = 0; j < 32; ++j) acc[j] = fmaf(xv, wp[j], acc[j]);
    }
  }
  int t = t0 + ttl;
#pragma unroll
  for (int j = 0; j < 32; ++j) {
    float v = acc[j];
    if constexpr (SKIP) v += skip[(b * 32 + j) * TB + t];
    out[(b * 32 + j) * TB + t] = fmaxf(v, 0.f);
  }
}

// code_assign (f64 distances/argmin, f32 q)
template <int M>
__global__ __launch_bounds__(256) void code_assign_kernel(
    const double* __restrict__ h, int coff, const float* __restrict__ means,
    float* __restrict__ q, float* __restrict__ idx_out) {
  __shared__ double ms[32 * M];
  __shared__ float msf[32 * M];
  __shared__ double msq[M];
  int b = blockIdx.y;
  int tid = threadIdx.x;
  int t = blockIdx.x * 256 + tid;
  for (int i = tid; i < 32 * M; i += 256) {
    float v = means[i];
    ms[i] = (double)v;
    msf[i] = v;
  }
  __syncthreads();
  if (tid < M) {
    double s = 0.0;
#pragma unroll
    for (int c = 0; c < 32; ++c) s = fma(ms[c * M + tid], ms[c * M + tid], s);
    msq[tid] = s;
  }
  __syncthreads();
  double xv[32];
  double sx = 0.0;
#pragma unroll
  for (int c = 0; c < 32; ++c) {
    xv[c] = h[(b * 64 + coff + c) * TB + t];
    sx = fma(xv[c], xv[c], sx);
  }
  double dmin = 1e300;
  int imin = 0;
  float ssum = 0.f;
  float qv[32];
#pragma unroll
  for (int c = 0; c < 32; ++c) qv[c] = 0.f;
  for (int m = 0; m < M; ++m) {
    double dot = 0.0;
#pragma unroll
    for (int c = 0; c < 32; ++c) dot = fma(xv[c], ms[c * M + m], dot);
    double d = sx - 2.0 * dot + msq[m];
    float p;
    if (d < dmin) {
      float f = expf((float)(d - dmin));
      ssum *= f;
#pragma unroll
      for (int c = 0; c < 32; ++c) qv[c] *= f;
      dmin = d;
      imin = m;
      p = 1.f;
    } else {
      p = expf((float)(dmin - d));
    }
    ssum += p;
#pragma unroll
    for (int c = 0; c < 32; ++c) qv[c] = fmaf(p, msf[c * M + m], qv[c]);
  }
  float inv = 1.f / ssum;
#pragma unroll
  for (int c = 0; c < 32; ++c) q[(b * 32 + c) * TB + t] = qv[c] * inv;
  idx_out[b * TB + t] = (float)imin;
}

// Split-K FC partial: Z [Mrows][16384], w [512][16384].
__global__ __launch_bounds__(256) void fc_partial_gemm(
    const float* __restrict__ Z, const float* __restrict__ w,
    float* __restrict__ PB, int Mrows) {
  constexpr int BK = 32;
  constexpr int KC = 2048;
  __shared__ float As[BK][68];
  __shared__ float Bs[BK][68];
  int m0 = blockIdx.y * 64;
  int n0 = blockIdx.x * 64;
  int kbase = blockIdx.z * KC;
  int tid = threadIdx.x;
  int row = tid >> 2;
  int kq = (tid & 3) * 4;
  const float* zrow = Z + (size_t)(m0 + row) * 16384 + kbase;
  const float* wrow = w + (size_t)(n0 + row) * 16384 + kbase;
  int mg = tid >> 4;
  int ng = tid & 15;
  float acc[4][4] = {};
  for (int k0 = 0; k0 < KC; k0 += BK) {
    float4 a0 = *(const float4*)&zrow[k0 + kq];
    float4 a1 = *(const float4*)&zrow[k0 + kq + 16];
    float4 b0 = *(const float4*)&wrow[k0 + kq];
    float4 b1 = *(const float4*)&wrow[k0 + kq + 16];
    __syncthreads();
    As[kq + 0][row] = a0.x; As[kq + 1][row] = a0.y;
    As[kq + 2][row] = a0.z; As[kq + 3][row] = a0.w;
    As[kq + 16][row] = a1.x; As[kq + 17][row] = a1.y;
    As[kq + 18][row] = a1.z; As[kq + 19][row] = a1.w;
    Bs[kq + 0][row] = b0.x; Bs[kq + 1][row] = b0.y;
    Bs[kq + 2][row] = b0.z; Bs[kq + 3][row] = b0.w;
    Bs[kq + 16][row] = b1.x; Bs[kq + 17][row] = b1.y;
    Bs[kq + 18][row] = b1.z; Bs[kq + 19][row] = b1.w;
    __syncthreads();
#pragma unroll
    for (int kk = 0; kk < BK; ++kk) {
      float4 av = *(const float4*)&As[kk][mg * 4];
      float4 bv = *(const float4*)&Bs[kk][ng * 4];
      acc[0][0] = fmaf(av.x, bv.x, acc[0][0]);
      acc[0][1] = fmaf(av.x, bv.y, acc[0][1]);
      acc[0][2] = fmaf(av.x, bv.z, acc[0][2]);
      acc[0][3] = fmaf(av.x, bv.w, acc[0][3]);
      acc[1][0] = fmaf(av.y, bv.x, acc[1][0]);
      acc[1][1] = fmaf(av.y, bv.y, acc[1][1]);
      acc[1][2] = fmaf(av.y, bv.z, acc[1][2]);
      acc[1][3] = fmaf(av.y, bv.w, acc[1][3]);
      acc[2][0] = fmaf(av.z, bv.x, acc[2][0]);
      acc[2][1] = fmaf(av.z, bv.y, acc[2][1]);
      acc[2][2] = fmaf(av.z, bv.z, acc[2][2]);
      acc[2][3] = fmaf(av.z, bv.w, acc[2][3]);
      acc[3][0] = fmaf(av.w, bv.x, acc[3][0]);
      acc[3][1] = fmaf(av.w, bv.y, acc[3][1]);
      acc[3][2] = fmaf(av.w, bv.z, acc[3][2]);
      acc[3][3] = fmaf(av.w, bv.w, acc[3][3]);
    }
  }
  float* pbase = PB + (size_t)blockIdx.z * Mrows * 512;
#pragma unroll
  for (int mi = 0; mi < 4; ++mi) {
    float4 v = {acc[mi][0], acc[mi][1], acc[mi][2], acc[mi][3]};
    *(float4*)&pbase[(size_t)(m0 + mg * 4 + mi) * 512 + n0 + ng * 4] = v;
  }
}

// Reduce KS partials + bias + tanh -> out rows (stacked streams)
__global__ __launch_bounds__(256) void fc_reduce_tanh(
    const float* __restrict__ PB, const float* __restrict__ bias,
    float* __restrict__ out, int Mrows, int rps, int c0) {
  constexpr int KS = 8;
  int idx = blockIdx.x * 256 + threadIdx.x;
  int m = idx >> 9, n = idx & 511;
  if (m >= Mrows) return;
  float s = bias[n];
#pragma unroll
  for (int ks = 0; ks < KS; ++ks)
    s += PB[((size_t)ks * Mrows + m) * 512 + n];
  int st = m / rps, rr = m - st * rps;
  out[((size_t)st * 1024 + c0 + rr) * 512 + n] = tanhf(s);
}

extern "C" void kernel_launch(void* const* d_in, const int* in_sizes, int n_in,
                              void* d_out, int out_size, void* d_ws,
                              size_t ws_size, hipStream_t stream) {
  const float* x = (const float*)d_in[0];
  const float* enc0_w1 = (const float*)d_in[1];
  const float* enc0_b1 = (const float*)d_in[2];
  const float* enc0_w2 = (const float*)d_in[3];
  const float* enc0_b2 = (const float*)d_in[4];
  const float* enc0_ws = (const float*)d_in[5];
  const float* enc0_bs = (const float*)d_in[6];
  const float* enc_w = (const float*)d_in[7];
  const float* enc_b = (const float*)d_in[8];
  const float* dec_w = (const float*)d_in[9];
  const float* dec_b = (const float*)d_in[10];
  const float* fc1_w = (const float*)d_in[11];
  const float* fc1_b = (const float*)d_in[12];
  const float* means_s = (const float*)d_in[13];
  const float* means_n = (const float*)d_in[14];

  const size_t WB = 2285568;  // transposed-weight bytes
  int BC = 32;
  for (int c = 512; c >= 32; c >>= 1)
    if (WB + (size_t)c * 524288 <= ws_size) { BC = c; break; }

  double* wT0d = (double*)d_ws;
  double* wTed = wT0d + 36864;
  float* wTdf = (float*)(wTed + 221184);
  double* E0d = (double*)(wTdf + 55296);
  double* E1d = E0d + (size_t)BC * 32768;
  float* qs = (float*)E1d;
  float* qn = qs + (size_t)BC * 16384;
  float* D0 = qn + (size_t)BC * 16384;
  float* T1 = D0 + (size_t)BC * 16384;
  float* Dz = (float*)E0d;                    // 2*BC*16384 floats
  float* PB = Dz + (size_t)2 * BC * 16384;    // 8*2*BC*512 floats
  float* out = (float*)d_out;

  transpose_w_f64_kernel<<<dim3(144), 256, 0, stream>>>(enc0_w2, wT0d, 64, 1);
  transpose_w_f64_kernel<<<dim3(864), 256, 0, stream>>>(enc_w, wTed, 64, 6);
  transpose_w_f32_kernel<<<dim3(216), 256, 0, stream>>>(dec_w, wTdf, 32, 6);

  for (int c0 = 0; c0 < BATCH; c0 += BC) {
    const float* xb = x + (size_t)c0 * TB;

    // encoder (f64)
    enc0_f64_kernel<<<dim3(8, BC), 256, 0, stream>>>(
        xb, enc0_w1, enc0_b1, wT0d, enc0_b2, enc0_ws, enc0_bs, E0d);
    for (int i = 0; i < 3; ++i) {
      conv64_f64_kernel<false><<<dim3(8, BC), 128, 0, stream>>>(
          E0d, wTed + (2 * i) * 36864, enc_b + (2 * i) * 64, nullptr, E1d);
      conv64_f64_kernel<true><<<dim3(8, BC), 128, 0, stream>>>(
          E1d, wTed + (2 * i + 1) * 36864, enc_b + (2 * i + 1) * 64, E0d, E0d);
    }

    // vector-quantize (writes idx outputs directly)
    code_assign_kernel<64><<<dim3(2, BC), 256, 0, stream>>>(
        E0d, 0, means_s, qs, out + 2 * 524288 + (size_t)c0 * TB);
    code_assign_kernel<32><<<dim3(2, BC), 256, 0, stream>>>(
        E0d, 32, means_n, qn, out + 3 * 524288 + (size_t)c0 * TB);

    // decoders; final z for stream s -> Dz rows [0,BC), n -> rows [BC,2BC)
    float* destS = Dz;
    float* destN = Dz + (size_t)BC * 16384;
    {
      float* outs[3] = {T1, qs, destS};
      const float* zin = qs;
      for (int i = 0; i < 3; ++i) {
        conv32_f32_kernel<false><<<dim3(4, BC), 128, 0, stream>>>(
            zin, wTdf + (2 * i) * 9216, dec_b + (2 * i) * 32, nullptr, D0);
        conv32_f32_kernel<true><<<dim3(4, BC), 128, 0, stream>>>(
            D0, wTdf + (2 * i + 1) * 9216, dec_b + (2 * i + 1) * 32, zin,
            outs[i]);
        zin = outs[i];
      }
    }
    {
      float* outs[3] = {T1, qn, destN};
      const float* zin = qn;
      for (int i = 0; i < 3; ++i) {
        conv32_f32_kernel<false><<<dim3(4, BC), 128, 0, stream>>>(
            zin, wTdf + (2 * i) * 9216, dec_b + (2 * i) * 32, nullptr, D0);
        conv32_f32_kernel<true><<<dim3(4, BC), 128, 0, stream>>>(
            D0, wTdf + (2 * i + 1) * 9216, dec_b + (2 * i + 1) * 32, zin,
            outs[i]);
        zin = outs[i];
      }
    }

    // FC: split-K partials + reduce
    fc_partial_gemm<<<dim3(8, (2 * BC) / 64, 8), 256, 0, stream>>>(
        Dz, fc1_w, PB, 2 * BC);
    fc_reduce_tanh<<<dim3((2 * BC * 512) / 256), 256, 0, stream>>>(
        PB, fc1_b, out, 2 * BC, BC, c0);
  }
}

// Round 8
// 8487.415 us; speedup vs baseline: 1.8964x; 1.8964x over previous
//
#include <hip/hip_runtime.h>
#include <math.h>

// ---------------------------------------------------------------------------
// AE_control: B=1024, T=512, D=64, K=9, NUM_M=64, NUM_N=32, SCALE=1
// Encoder + argmin in f64 (idx needs exact argmin vs f64 np reference).
// R8: conv64 re-decomposed lane=cout: weights via coalesced global vector
// loads (vmcnt), x via uniform ds_read_b128 broadcasts. FMA order bit-exact
// to round-5 (passing) version. Decoder + FC f32 (round-5 proven). BC=256.
// ---------------------------------------------------------------------------

#define TB 512
#define BATCH 1024

// (nmat, C, C, 9) f32 -> (nmat, 9, C, C) f64  [k][cin][cout]
__global__ __launch_bounds__(256) void transpose_w_f64_kernel(
    const float* __restrict__ w, double* __restrict__ wT, int C, int nmat) {
  int total = nmat * C * C * 9;
  for (int i = blockIdx.x * blockDim.x + threadIdx.x; i < total;
       i += gridDim.x * blockDim.x) {
    int mat = i / (C * C * 9);
    int r = i % (C * C * 9);
    int cout = r / (C * 9);
    int rem = r % (C * 9);
    int cin = rem / 9;
    int k = rem % 9;
    wT[mat * C * C * 9 + (k * C + cin) * C + cout] = (double)w[i];
  }
}

// (nmat, C, C, 9) f32 -> (nmat, 9, C, C) f32
__global__ __launch_bounds__(256) void transpose_w_f32_kernel(
    const float* __restrict__ w, float* __restrict__ wT, int C, int nmat) {
  int total = nmat * C * C * 9;
  for (int i = blockIdx.x * blockDim.x + threadIdx.x; i < total;
       i += gridDim.x * blockDim.x) {
    int mat = i / (C * C * 9);
    int r = i % (C * C * 9);
    int cout = r / (C * 9);
    int rem = r % (C * 9);
    int cin = rem / 9;
    int k = rem % 9;
    wT[mat * C * C * 9 + (k * C + cin) * C + cout] = w[i];
  }
}

// Core f64 conv body: lane = cout (64 lanes), wave = t-slab (16 t each).
// src: LDS [64][72] (tt=0 <-> t0-4). wT: global [k][cin][cout] (per-lane
// coalesced loads). acc[t] accumulates in cin-major, k-inner order —
// bit-identical to the round-5 sequential form.
__device__ __forceinline__ void conv64_body(const double* __restrict__ xs,
                                            const double* __restrict__ wT,
                                            double acc[16], int lane,
                                            int wslab) {
  for (int cin = 0; cin < 64; ++cin) {
    const double* xr = xs + cin * 72 + wslab * 16;
    double xwin[24];
#pragma unroll
    for (int i = 0; i < 24; ++i) xwin[i] = xr[i];  // uniform -> broadcast
    const double* wp = wT + cin * 64 + lane;       // per-lane, coalesced
#pragma unroll
    for (int k = 0; k < 9; ++k) {
      double w = wp[k * 4096];
#pragma unroll
      for (int t = 0; t < 16; ++t) acc[t] = fma(w, xwin[t + k], acc[t]);
    }
  }
}

// enc0 fused block (f64): x f32 (BC,512) -> out f64 (BC,64,512)
__global__ __launch_bounds__(256) void enc0_f64_kernel(
    const float* __restrict__ x, const float* __restrict__ w1,
    const float* __restrict__ b1, const double* __restrict__ w2T,
    const float* __restrict__ b2, const float* __restrict__ wsc,
    const float* __restrict__ bsc, double* __restrict__ out) {
  __shared__ double xs0[80];
  __shared__ double w1s[576];
  __shared__ double b1s[64];
  __shared__ double mid[64 * 72];
  int b = blockIdx.y;
  int t0 = blockIdx.x * 64;
  int tid = threadIdx.x;
  if (tid < 80) {
    int t = t0 - 8 + tid;
    xs0[tid] = (t >= 0 && t < TB) ? (double)x[b * TB + t] : 0.0;
  }
  for (int i = tid; i < 576; i += 256) w1s[i] = (double)w1[i];
  if (tid < 64) b1s[tid] = (double)b1[tid];
  __syncthreads();
  // mid[cout][tt], tt in [0,72): t = t0-4+tt ; zero outside [0,TB) (SAME pad)
  for (int e = tid; e < 64 * 72; e += 256) {
    int cout = e / 72, tt = e % 72;
    int t = t0 - 4 + tt;
    double acc = b1s[cout];
#pragma unroll
    for (int k = 0; k < 9; ++k) acc = fma(w1s[cout * 9 + k], xs0[tt + k], acc);
    mid[e] = (t >= 0 && t < TB) ? fmax(acc, 0.0) : 0.0;
  }
  __syncthreads();
  int wave = tid >> 6;
  int lane = tid & 63;
  double acc[16];
  double bz = (double)b2[lane];
#pragma unroll
  for (int t = 0; t < 16; ++t) acc[t] = bz;
  conv64_body(mid, w2T, acc, lane, wave);
  __syncthreads();  // mid reads done; reuse as transpose buffer [64][65]
  double* T = mid;
#pragma unroll
  for (int t = 0; t < 16; ++t) T[lane * 65 + wave * 16 + t] = acc[t];
  __syncthreads();
  for (int i = tid; i < 4096; i += 256) {
    int cout = i >> 6, tt = i & 63;
    double v = T[cout * 65 + tt] +
               fma((double)wsc[cout], xs0[8 + tt], (double)bsc[cout]);
    out[(b * 64 + cout) * TB + t0 + tt] = fmax(v, 0.0);
  }
}

// f64 conv 64->64, K=9, SAME. out = relu(conv(in)+bias [+ skip])
template <bool SKIP>
__global__ __launch_bounds__(256) void conv64_f64_kernel(
    const double* __restrict__ in, const double* __restrict__ wT,
    const float* __restrict__ bias, const double* __restrict__ skip,
    double* __restrict__ out) {
  __shared__ double xs[64 * 72];
  int b = blockIdx.y;
  int t0 = blockIdx.x * 64;
  int tid = threadIdx.x;
  for (int i = tid; i < 64 * 72; i += 256) {
    int cin = i / 72, tt = i % 72;
    int t = t0 - 4 + tt;
    xs[i] = (t >= 0 && t < TB) ? in[(b * 64 + cin) * TB + t] : 0.0;
  }
  __syncthreads();
  int wave = tid >> 6;
  int lane = tid & 63;
  double acc[16];
  double bz = (double)bias[lane];
#pragma unroll
  for (int t = 0; t < 16; ++t) acc[t] = bz;
  conv64_body(xs, wT, acc, lane, wave);
  __syncthreads();  // xs reads done; reuse as transpose buffer [64][65]
  double* T = xs;
#pragma unroll
  for (int t = 0; t < 16; ++t) T[lane * 65 + wave * 16 + t] = acc[t];
  __syncthreads();
  for (int i = tid; i < 4096; i += 256) {
    int cout = i >> 6, tt = i & 63;
    double v = T[cout * 65 + tt];
    if constexpr (SKIP) v += skip[(b * 64 + cout) * TB + t0 + tt];
    out[(b * 64 + cout) * TB + t0 + tt] = fmax(v, 0.0);
  }
}

// f32 conv 32->32 (decoder), K=9, SAME  [round-5 proven form]
template <bool SKIP>
__global__ __launch_bounds__(256) void conv32_f32_kernel(
    const float* __restrict__ in, const float* __restrict__ wT,
    const float* __restrict__ bias, const float* __restrict__ skip,
    float* __restrict__ out) {
  constexpr int XW = 136;
  __shared__ float xs[32 * XW];
  int b = blockIdx.y;
  int t0 = blockIdx.x * 128;
  int tid = threadIdx.x;
  for (int i = tid; i < 32 * XW; i += 256) {
    int cin = i / XW, tt = i % XW;
    int t = t0 - 4 + tt;
    xs[i] = (t >= 0 && t < TB) ? in[(b * 32 + cin) * TB + t] : 0.f;
  }
  __syncthreads();
  int wave = __builtin_amdgcn_readfirstlane(tid >> 6);
  int lane = tid & 63;
  int cbase = (wave & 1) * 16;
  int ttl = (wave >> 1) * 64 + lane;
  float acc[16];
#pragma unroll
  for (int j = 0; j < 16; ++j) acc[j] = bias[cbase + j];
  for (int cin = 0; cin < 32; ++cin) {
#pragma unroll
    for (int k = 0; k < 9; ++k) {
      float xv = xs[cin * XW + ttl + k];
      const float* wp = wT + (k * 32 + cin) * 32 + cbase;
#pragma unroll
      for (int j = 0; j < 16; ++j) acc[j] = fmaf(xv, wp[j], acc[j]);
    }
  }
  int t = t0 + ttl;
#pragma unroll
  for (int j = 0; j < 16; ++j) {
    float v = acc[j];
    if constexpr (SKIP) v += skip[(b * 32 + cbase + j) * TB + t];
    out[(b * 32 + cbase + j) * TB + t] = fmaxf(v, 0.f);
  }
}

// code_assign (f64 distances/argmin, f32 q)
template <int M>
__global__ __launch_bounds__(256) void code_assign_kernel(
    const double* __restrict__ h, int coff, const float* __restrict__ means,
    float* __restrict__ q, float* __restrict__ idx_out) {
  __shared__ double ms[32 * M];
  __shared__ float msf[32 * M];
  __shared__ double msq[M];
  int b = blockIdx.y;
  int tid = threadIdx.x;
  int t = blockIdx.x * 256 + tid;
  for (int i = tid; i < 32 * M; i += 256) {
    float v = means[i];
    ms[i] = (double)v;
    msf[i] = v;
  }
  __syncthreads();
  if (tid < M) {
    double s = 0.0;
#pragma unroll
    for (int c = 0; c < 32; ++c) s = fma(ms[c * M + tid], ms[c * M + tid], s);
    msq[tid] = s;
  }
  __syncthreads();
  double xv[32];
  double sx = 0.0;
#pragma unroll
  for (int c = 0; c < 32; ++c) {
    xv[c] = h[(b * 64 + coff + c) * TB + t];
    sx = fma(xv[c], xv[c], sx);
  }
  double dmin = 1e300;
  int imin = 0;
  float ssum = 0.f;
  float qv[32];
#pragma unroll
  for (int c = 0; c < 32; ++c) qv[c] = 0.f;
  for (int m = 0; m < M; ++m) {
    double dot = 0.0;
#pragma unroll
    for (int c = 0; c < 32; ++c) dot = fma(xv[c], ms[c * M + m], dot);
    double d = sx - 2.0 * dot + msq[m];
    float p;
    if (d < dmin) {
      float f = expf((float)(d - dmin));
      ssum *= f;
#pragma unroll
      for (int c = 0; c < 32; ++c) qv[c] *= f;
      dmin = d;
      imin = m;
      p = 1.f;
    } else {
      p = expf((float)(dmin - d));
    }
    ssum += p;
#pragma unroll
    for (int c = 0; c < 32; ++c) qv[c] = fmaf(p, msf[c * M + m], qv[c]);
  }
  float inv = 1.f / ssum;
#pragma unroll
  for (int c = 0; c < 32; ++c) q[(b * 32 + c) * TB + t] = qv[c] * inv;
  idx_out[b * TB + t] = (float)imin;
}

// Split-K FC partial: Z [Mrows][16384], w [512][16384].
__global__ __launch_bounds__(256) void fc_partial_gemm(
    const float* __restrict__ Z, const float* __restrict__ w,
    float* __restrict__ PB, int Mrows) {
  constexpr int BK = 32;
  constexpr int KC = 2048;
  __shared__ float As[BK][68];
  __shared__ float Bs[BK][68];
  int m0 = blockIdx.y * 64;
  int n0 = blockIdx.x * 64;
  int kbase = blockIdx.z * KC;
  int tid = threadIdx.x;
  int row = tid >> 2;
  int kq = (tid & 3) * 4;
  const float* zrow = Z + (size_t)(m0 + row) * 16384 + kbase;
  const float* wrow = w + (size_t)(n0 + row) * 16384 + kbase;
  int mg = tid >> 4;
  int ng = tid & 15;
  float acc[4][4] = {};
  for (int k0 = 0; k0 < KC; k0 += BK) {
    float4 a0 = *(const float4*)&zrow[k0 + kq];
    float4 a1 = *(const float4*)&zrow[k0 + kq + 16];
    float4 b0 = *(const float4*)&wrow[k0 + kq];
    float4 b1 = *(const float4*)&wrow[k0 + kq + 16];
    __syncthreads();
    As[kq + 0][row] = a0.x; As[kq + 1][row] = a0.y;
    As[kq + 2][row] = a0.z; As[kq + 3][row] = a0.w;
    As[kq + 16][row] = a1.x; As[kq + 17][row] = a1.y;
    As[kq + 18][row] = a1.z; As[kq + 19][row] = a1.w;
    Bs[kq + 0][row] = b0.x; Bs[kq + 1][row] = b0.y;
    Bs[kq + 2][row] = b0.z; Bs[kq + 3][row] = b0.w;
    Bs[kq + 16][row] = b1.x; Bs[kq + 17][row] = b1.y;
    Bs[kq + 18][row] = b1.z; Bs[kq + 19][row] = b1.w;
    __syncthreads();
#pragma unroll
    for (int kk = 0; kk < BK; ++kk) {
      float4 av = *(const float4*)&As[kk][mg * 4];
      float4 bv = *(const float4*)&Bs[kk][ng * 4];
      acc[0][0] = fmaf(av.x, bv.x, acc[0][0]);
      acc[0][1] = fmaf(av.x, bv.y, acc[0][1]);
      acc[0][2] = fmaf(av.x, bv.z, acc[0][2]);
      acc[0][3] = fmaf(av.x, bv.w, acc[0][3]);
      acc[1][0] = fmaf(av.y, bv.x, acc[1][0]);
      acc[1][1] = fmaf(av.y, bv.y, acc[1][1]);
      acc[1][2] = fmaf(av.y, bv.z, acc[1][2]);
      acc[1][3] = fmaf(av.y, bv.w, acc[1][3]);
      acc[2][0] = fmaf(av.z, bv.x, acc[2][0]);
      acc[2][1] = fmaf(av.z, bv.y, acc[2][1]);
      acc[2][2] = fmaf(av.z, bv.z, acc[2][2]);
      acc[2][3] = fmaf(av.z, bv.w, acc[2][3]);
      acc[3][0] = fmaf(av.w, bv.x, acc[3][0]);
      acc[3][1] = fmaf(av.w, bv.y, acc[3][1]);
      acc[3][2] = fmaf(av.w, bv.z, acc[3][2]);
      acc[3][3] = fmaf(av.w, bv.w, acc[3][3]);
    }
  }
  float* pbase = PB + (size_t)blockIdx.z * Mrows * 512;
#pragma unroll
  for (int mi = 0; mi < 4; ++mi) {
    float4 v = {acc[mi][0], acc[mi][1], acc[mi][2], acc[mi][3]};
    *(float4*)&pbase[(size_t)(m0 + mg * 4 + mi) * 512 + n0 + ng * 4] = v;
  }
}

// Reduce KS partials + bias + tanh -> out rows (stacked streams)
__global__ __launch_bounds__(256) void fc_reduce_tanh(
    const float* __restrict__ PB, const float* __restrict__ bias,
    float* __restrict__ out, int Mrows, int rps, int c0) {
  constexpr int KS = 8;
  int idx = blockIdx.x * 256 + threadIdx.x;
  int m = idx >> 9, n = idx & 511;
  if (m >= Mrows) return;
  float s = bias[n];
#pragma unroll
  for (int ks = 0; ks < KS; ++ks)
    s += PB[((size_t)ks * Mrows + m) * 512 + n];
  int st = m / rps, rr = m - st * rps;
  out[((size_t)st * 1024 + c0 + rr) * 512 + n] = tanhf(s);
}

extern "C" void kernel_launch(void* const* d_in, const int* in_sizes, int n_in,
                              void* d_out, int out_size, void* d_ws,
                              size_t ws_size, hipStream_t stream) {
  const float* x = (const float*)d_in[0];
  const float* enc0_w1 = (const float*)d_in[1];
  const float* enc0_b1 = (const float*)d_in[2];
  const float* enc0_w2 = (const float*)d_in[3];
  const float* enc0_b2 = (const float*)d_in[4];
  const float* enc0_ws = (const float*)d_in[5];
  const float* enc0_bs = (const float*)d_in[6];
  const float* enc_w = (const float*)d_in[7];
  const float* enc_b = (const float*)d_in[8];
  const float* dec_w = (const float*)d_in[9];
  const float* dec_b = (const float*)d_in[10];
  const float* fc1_w = (const float*)d_in[11];
  const float* fc1_b = (const float*)d_in[12];
  const float* means_s = (const float*)d_in[13];
  const float* means_n = (const float*)d_in[14];

  const size_t WB = 2285568;  // transposed-weight bytes
  int BC = 32;
  for (int c = 512; c >= 32; c >>= 1)
    if (WB + (size_t)c * 524288 <= ws_size) { BC = c; break; }

  double* wT0d = (double*)d_ws;
  double* wTed = wT0d + 36864;
  float* wTdf = (float*)(wTed + 221184);
  double* E0d = (double*)(wTdf + 55296);
  double* E1d = E0d + (size_t)BC * 32768;
  float* qs = (float*)E1d;
  float* qn = qs + (size_t)BC * 16384;
  float* D0 = qn + (size_t)BC * 16384;
  float* T1 = D0 + (size_t)BC * 16384;
  float* Dz = (float*)E0d;                    // 2*BC*16384 floats
  float* PB = Dz + (size_t)2 * BC * 16384;    // 8*2*BC*512 floats
  float* out = (float*)d_out;

  transpose_w_f64_kernel<<<dim3(144), 256, 0, stream>>>(enc0_w2, wT0d, 64, 1);
  transpose_w_f64_kernel<<<dim3(864), 256, 0, stream>>>(enc_w, wTed, 64, 6);
  transpose_w_f32_kernel<<<dim3(216), 256, 0, stream>>>(dec_w, wTdf, 32, 6);

  for (int c0 = 0; c0 < BATCH; c0 += BC) {
    const float* xb = x + (size_t)c0 * TB;

    // encoder (f64)
    enc0_f64_kernel<<<dim3(8, BC), 256, 0, stream>>>(
        xb, enc0_w1, enc0_b1, wT0d, enc0_b2, enc0_ws, enc0_bs, E0d);
    for (int i = 0; i < 3; ++i) {
      conv64_f64_kernel<false><<<dim3(8, BC), 256, 0, stream>>>(
          E0d, wTed + (2 * i) * 36864, enc_b + (2 * i) * 64, nullptr, E1d);
      conv64_f64_kernel<true><<<dim3(8, BC), 256, 0, stream>>>(
          E1d, wTed + (2 * i + 1) * 36864, enc_b + (2 * i + 1) * 64, E0d, E0d);
    }

    // vector-quantize (writes idx outputs directly)
    code_assign_kernel<64><<<dim3(2, BC), 256, 0, stream>>>(
        E0d, 0, means_s, qs, out + 2 * 524288 + (size_t)c0 * TB);
    code_assign_kernel<32><<<dim3(2, BC), 256, 0, stream>>>(
        E0d, 32, means_n, qn, out + 3 * 524288 + (size_t)c0 * TB);

    // decoders; final z for stream s -> Dz rows [0,BC), n -> rows [BC,2BC)
    float* destS = Dz;
    float* destN = Dz + (size_t)BC * 16384;
    {
      float* outs[3] = {T1, qs, destS};
      const float* zin = qs;
      for (int i = 0; i < 3; ++i) {
        conv32_f32_kernel<false><<<dim3(4, BC), 256, 0, stream>>>(
            zin, wTdf + (2 * i) * 9216, dec_b + (2 * i) * 32, nullptr, D0);
        conv32_f32_kernel<true><<<dim3(4, BC), 256, 0, stream>>>(
            D0, wTdf + (2 * i + 1) * 9216, dec_b + (2 * i + 1) * 32, zin,
            outs[i]);
        zin = outs[i];
      }
    }
    {
      float* outs[3] = {T1, qn, destN};
      const float* zin = qn;
      for (int i = 0; i < 3; ++i) {
        conv32_f32_kernel<false><<<dim3(4, BC), 256, 0, stream>>>(
            zin, wTdf + (2 * i) * 9216, dec_b + (2 * i) * 32, nullptr, D0);
        conv32_f32_kernel<true><<<dim3(4, BC), 256, 0, stream>>>(
            D0, wTdf + (2 * i + 1) * 9216, dec_b + (2 * i + 1) * 32, zin,
            outs[i]);
        zin = outs[i];
      }
    }

    // FC: split-K partials + reduce
    fc_partial_gemm<<<dim3(8, (2 * BC) / 64, 8), 256, 0, stream>>>(
        Dz, fc1_w, PB, 2 * BC);
    fc_reduce_tanh<<<dim3((2 * BC * 512) / 256), 256, 0, stream>>>(
        PB, fc1_b, out, 2 * BC, BC, c0);
  }
}

// Round 9
// 8410.310 us; speedup vs baseline: 1.9137x; 1.0092x over previous
//
#include <hip/hip_runtime.h>
#include <math.h>

// ---------------------------------------------------------------------------
// AE_control: B=1024, T=512, D=64, K=9, NUM_M=64, NUM_N=32, SCALE=1
// Encoder + argmin in f64 (idx needs exact argmin vs f64 np reference).
// R9: conv64 body register-pipelined (launch_bounds(256,1), xw+weights in
// VGPRs, next-cin weight prefetch). FMA order unchanged (cin asc, k asc).
// Decoder + FC f32 (round-5 proven). BC=256.
// ---------------------------------------------------------------------------

#define TB 512
#define BATCH 1024

// (nmat, C, C, 9) f32 -> (nmat, 9, C, C) f64  [k][cin][cout]
__global__ __launch_bounds__(256) void transpose_w_f64_kernel(
    const float* __restrict__ w, double* __restrict__ wT, int C, int nmat) {
  int total = nmat * C * C * 9;
  for (int i = blockIdx.x * blockDim.x + threadIdx.x; i < total;
       i += gridDim.x * blockDim.x) {
    int mat = i / (C * C * 9);
    int r = i % (C * C * 9);
    int cout = r / (C * 9);
    int rem = r % (C * 9);
    int cin = rem / 9;
    int k = rem % 9;
    wT[mat * C * C * 9 + (k * C + cin) * C + cout] = (double)w[i];
  }
}

// (nmat, C, C, 9) f32 -> (nmat, 9, C, C) f32
__global__ __launch_bounds__(256) void transpose_w_f32_kernel(
    const float* __restrict__ w, float* __restrict__ wT, int C, int nmat) {
  int total = nmat * C * C * 9;
  for (int i = blockIdx.x * blockDim.x + threadIdx.x; i < total;
       i += gridDim.x * blockDim.x) {
    int mat = i / (C * C * 9);
    int r = i % (C * C * 9);
    int cout = r / (C * 9);
    int rem = r % (C * 9);
    int cin = rem / 9;
    int k = rem % 9;
    wT[mat * C * C * 9 + (k * C + cin) * C + cout] = w[i];
  }
}

// Core f64 conv body: lane = cout (64 lanes), wave = t-slab (16 t each).
// src: LDS [64][72] (tt=0 <-> t0-4). wT: global [k][cin][cout] (per-lane
// coalesced loads). acc[t] accumulates cin-major, k-inner — same order as the
// round-5/8 passing versions. Pipelined: xw + current weights in registers,
// next-cin weights prefetched during FMA.
__device__ __forceinline__ void conv64_body(const double* __restrict__ xs,
                                            const double* __restrict__ wT,
                                            double acc[16], int lane,
                                            int wslab) {
  double w[9];
  {
    const double* wp = wT + lane;  // cin = 0
#pragma unroll
    for (int k = 0; k < 9; ++k) w[k] = wp[k * 4096];
  }
  for (int cin = 0; cin < 64; ++cin) {
    const double* xr = xs + cin * 72 + wslab * 16;
    double xw[24];
#pragma unroll
    for (int i = 0; i < 24; ++i) xw[i] = xr[i];  // uniform -> LDS broadcast
    double wc[9];
#pragma unroll
    for (int k = 0; k < 9; ++k) wc[k] = w[k];
    if (cin + 1 < 64) {
      const double* wpn = wT + (cin + 1) * 64 + lane;
#pragma unroll
      for (int k = 0; k < 9; ++k) w[k] = wpn[k * 4096];  // prefetch next cin
    }
#pragma unroll
    for (int k = 0; k < 9; ++k) {
#pragma unroll
      for (int t = 0; t < 16; ++t) acc[t] = fma(wc[k], xw[t + k], acc[t]);
    }
  }
}

// enc0 fused block (f64): x f32 (BC,512) -> out f64 (BC,64,512)
__global__ __launch_bounds__(256, 1) void enc0_f64_kernel(
    const float* __restrict__ x, const float* __restrict__ w1,
    const float* __restrict__ b1, const double* __restrict__ w2T,
    const float* __restrict__ b2, const float* __restrict__ wsc,
    const float* __restrict__ bsc, double* __restrict__ out) {
  __shared__ double xs0[80];
  __shared__ double w1s[576];
  __shared__ double b1s[64];
  __shared__ double mid[64 * 72];
  int b = blockIdx.y;
  int t0 = blockIdx.x * 64;
  int tid = threadIdx.x;
  if (tid < 80) {
    int t = t0 - 8 + tid;
    xs0[tid] = (t >= 0 && t < TB) ? (double)x[b * TB + t] : 0.0;
  }
  for (int i = tid; i < 576; i += 256) w1s[i] = (double)w1[i];
  if (tid < 64) b1s[tid] = (double)b1[tid];
  __syncthreads();
  // mid[cout][tt], tt in [0,72): t = t0-4+tt ; zero outside [0,TB) (SAME pad)
  for (int e = tid; e < 64 * 72; e += 256) {
    int cout = e / 72, tt = e % 72;
    int t = t0 - 4 + tt;
    double acc = b1s[cout];
#pragma unroll
    for (int k = 0; k < 9; ++k) acc = fma(w1s[cout * 9 + k], xs0[tt + k], acc);
    mid[e] = (t >= 0 && t < TB) ? fmax(acc, 0.0) : 0.0;
  }
  __syncthreads();
  int wave = tid >> 6;
  int lane = tid & 63;
  double acc[16];
  double bz = (double)b2[lane];
#pragma unroll
  for (int t = 0; t < 16; ++t) acc[t] = bz;
  conv64_body(mid, w2T, acc, lane, wave);
  __syncthreads();  // mid reads done; reuse as transpose buffer [64][65]
  double* T = mid;
#pragma unroll
  for (int t = 0; t < 16; ++t) T[lane * 65 + wave * 16 + t] = acc[t];
  __syncthreads();
  for (int i = tid; i < 4096; i += 256) {
    int cout = i >> 6, tt = i & 63;
    double v = T[cout * 65 + tt] +
               fma((double)wsc[cout], xs0[8 + tt], (double)bsc[cout]);
    out[(b * 64 + cout) * TB + t0 + tt] = fmax(v, 0.0);
  }
}

// f64 conv 64->64, K=9, SAME. out = relu(conv(in)+bias [+ skip])
template <bool SKIP>
__global__ __launch_bounds__(256, 1) void conv64_f64_kernel(
    const double* __restrict__ in, const double* __restrict__ wT,
    const float* __restrict__ bias, const double* __restrict__ skip,
    double* __restrict__ out) {
  __shared__ double xs[64 * 72];
  int b = blockIdx.y;
  int t0 = blockIdx.x * 64;
  int tid = threadIdx.x;
  for (int i = tid; i < 64 * 72; i += 256) {
    int cin = i / 72, tt = i % 72;
    int t = t0 - 4 + tt;
    xs[i] = (t >= 0 && t < TB) ? in[(b * 64 + cin) * TB + t] : 0.0;
  }
  __syncthreads();
  int wave = tid >> 6;
  int lane = tid & 63;
  double acc[16];
  double bz = (double)bias[lane];
#pragma unroll
  for (int t = 0; t < 16; ++t) acc[t] = bz;
  conv64_body(xs, wT, acc, lane, wave);
  __syncthreads();  // xs reads done; reuse as transpose buffer [64][65]
  double* T = xs;
#pragma unroll
  for (int t = 0; t < 16; ++t) T[lane * 65 + wave * 16 + t] = acc[t];
  __syncthreads();
  for (int i = tid; i < 4096; i += 256) {
    int cout = i >> 6, tt = i & 63;
    double v = T[cout * 65 + tt];
    if constexpr (SKIP) v += skip[(b * 64 + cout) * TB + t0 + tt];
    out[(b * 64 + cout) * TB + t0 + tt] = fmax(v, 0.0);
  }
}

// f32 conv 32->32 (decoder), K=9, SAME  [round-5 proven form]
template <bool SKIP>
__global__ __launch_bounds__(256) void conv32_f32_kernel(
    const float* __restrict__ in, const float* __restrict__ wT,
    const float* __restrict__ bias, const float* __restrict__ skip,
    float* __restrict__ out) {
  constexpr int XW = 136;
  __shared__ float xs[32 * XW];
  int b = blockIdx.y;
  int t0 = blockIdx.x * 128;
  int tid = threadIdx.x;
  for (int i = tid; i < 32 * XW; i += 256) {
    int cin = i / XW, tt = i % XW;
    int t = t0 - 4 + tt;
    xs[i] = (t >= 0 && t < TB) ? in[(b * 32 + cin) * TB + t] : 0.f;
  }
  __syncthreads();
  int wave = __builtin_amdgcn_readfirstlane(tid >> 6);
  int lane = tid & 63;
  int cbase = (wave & 1) * 16;
  int ttl = (wave >> 1) * 64 + lane;
  float acc[16];
#pragma unroll
  for (int j = 0; j < 16; ++j) acc[j] = bias[cbase + j];
  for (int cin = 0; cin < 32; ++cin) {
#pragma unroll
    for (int k = 0; k < 9; ++k) {
      float xv = xs[cin * XW + ttl + k];
      const float* wp = wT + (k * 32 + cin) * 32 + cbase;
#pragma unroll
      for (int j = 0; j < 16; ++j) acc[j] = fmaf(xv, wp[j], acc[j]);
    }
  }
  int t = t0 + ttl;
#pragma unroll
  for (int j = 0; j < 16; ++j) {
    float v = acc[j];
    if constexpr (SKIP) v += skip[(b * 32 + cbase + j) * TB + t];
    out[(b * 32 + cbase + j) * TB + t] = fmaxf(v, 0.f);
  }
}

// code_assign (f64 distances/argmin, f32 q)
template <int M>
__global__ __launch_bounds__(256) void code_assign_kernel(
    const double* __restrict__ h, int coff, const float* __restrict__ means,
    float* __restrict__ q, float* __restrict__ idx_out) {
  __shared__ double ms[32 * M];
  __shared__ float msf[32 * M];
  __shared__ double msq[M];
  int b = blockIdx.y;
  int tid = threadIdx.x;
  int t = blockIdx.x * 256 + tid;
  for (int i = tid; i < 32 * M; i += 256) {
    float v = means[i];
    ms[i] = (double)v;
    msf[i] = v;
  }
  __syncthreads();
  if (tid < M) {
    double s = 0.0;
#pragma unroll
    for (int c = 0; c < 32; ++c) s = fma(ms[c * M + tid], ms[c * M + tid], s);
    msq[tid] = s;
  }
  __syncthreads();
  double xv[32];
  double sx = 0.0;
#pragma unroll
  for (int c = 0; c < 32; ++c) {
    xv[c] = h[(b * 64 + coff + c) * TB + t];
    sx = fma(xv[c], xv[c], sx);
  }
  double dmin = 1e300;
  int imin = 0;
  float ssum = 0.f;
  float qv[32];
#pragma unroll
  for (int c = 0; c < 32; ++c) qv[c] = 0.f;
  for (int m = 0; m < M; ++m) {
    double dot = 0.0;
#pragma unroll
    for (int c = 0; c < 32; ++c) dot = fma(xv[c], ms[c * M + m], dot);
    double d = sx - 2.0 * dot + msq[m];
    float p;
    if (d < dmin) {
      float f = expf((float)(d - dmin));
      ssum *= f;
#pragma unroll
      for (int c = 0; c < 32; ++c) qv[c] *= f;
      dmin = d;
      imin = m;
      p = 1.f;
    } else {
      p = expf((float)(dmin - d));
    }
    ssum += p;
#pragma unroll
    for (int c = 0; c < 32; ++c) qv[c] = fmaf(p, msf[c * M + m], qv[c]);
  }
  float inv = 1.f / ssum;
#pragma unroll
  for (int c = 0; c < 32; ++c) q[(b * 32 + c) * TB + t] = qv[c] * inv;
  idx_out[b * TB + t] = (float)imin;
}

// Split-K FC partial: Z [Mrows][16384], w [512][16384].
__global__ __launch_bounds__(256) void fc_partial_gemm(
    const float* __restrict__ Z, const float* __restrict__ w,
    float* __restrict__ PB, int Mrows) {
  constexpr int BK = 32;
  constexpr int KC = 2048;
  __shared__ float As[BK][68];
  __shared__ float Bs[BK][68];
  int m0 = blockIdx.y * 64;
  int n0 = blockIdx.x * 64;
  int kbase = blockIdx.z * KC;
  int tid = threadIdx.x;
  int row = tid >> 2;
  int kq = (tid & 3) * 4;
  const float* zrow = Z + (size_t)(m0 + row) * 16384 + kbase;
  const float* wrow = w + (size_t)(n0 + row) * 16384 + kbase;
  int mg = tid >> 4;
  int ng = tid & 15;
  float acc[4][4] = {};
  for (int k0 = 0; k0 < KC; k0 += BK) {
    float4 a0 = *(const float4*)&zrow[k0 + kq];
    float4 a1 = *(const float4*)&zrow[k0 + kq + 16];
    float4 b0 = *(const float4*)&wrow[k0 + kq];
    float4 b1 = *(const float4*)&wrow[k0 + kq + 16];
    __syncthreads();
    As[kq + 0][row] = a0.x; As[kq + 1][row] = a0.y;
    As[kq + 2][row] = a0.z; As[kq + 3][row] = a0.w;
    As[kq + 16][row] = a1.x; As[kq + 17][row] = a1.y;
    As[kq + 18][row] = a1.z; As[kq + 19][row] = a1.w;
    Bs[kq + 0][row] = b0.x; Bs[kq + 1][row] = b0.y;
    Bs[kq + 2][row] = b0.z; Bs[kq + 3][row] = b0.w;
    Bs[kq + 16][row] = b1.x; Bs[kq + 17][row] = b1.y;
    Bs[kq + 18][row] = b1.z; Bs[kq + 19][row] = b1.w;
    __syncthreads();
#pragma unroll
    for (int kk = 0; kk < BK; ++kk) {
      float4 av = *(const float4*)&As[kk][mg * 4];
      float4 bv = *(const float4*)&Bs[kk][ng * 4];
      acc[0][0] = fmaf(av.x, bv.x, acc[0][0]);
      acc[0][1] = fmaf(av.x, bv.y, acc[0][1]);
      acc[0][2] = fmaf(av.x, bv.z, acc[0][2]);
      acc[0][3] = fmaf(av.x, bv.w, acc[0][3]);
      acc[1][0] = fmaf(av.y, bv.x, acc[1][0]);
      acc[1][1] = fmaf(av.y, bv.y, acc[1][1]);
      acc[1][2] = fmaf(av.y, bv.z, acc[1][2]);
      acc[1][3] = fmaf(av.y, bv.w, acc[1][3]);
      acc[2][0] = fmaf(av.z, bv.x, acc[2][0]);
      acc[2][1] = fmaf(av.z, bv.y, acc[2][1]);
      acc[2][2] = fmaf(av.z, bv.z, acc[2][2]);
      acc[2][3] = fmaf(av.z, bv.w, acc[2][3]);
      acc[3][0] = fmaf(av.w, bv.x, acc[3][0]);
      acc[3][1] = fmaf(av.w, bv.y, acc[3][1]);
      acc[3][2] = fmaf(av.w, bv.z, acc[3][2]);
      acc[3][3] = fmaf(av.w, bv.w, acc[3][3]);
    }
  }
  float* pbase = PB + (size_t)blockIdx.z * Mrows * 512;
#pragma unroll
  for (int mi = 0; mi < 4; ++mi) {
    float4 v = {acc[mi][0], acc[mi][1], acc[mi][2], acc[mi][3]};
    *(float4*)&pbase[(size_t)(m0 + mg * 4 + mi) * 512 + n0 + ng * 4] = v;
  }
}

// Reduce KS partials + bias + tanh -> out rows (stacked streams)
__global__ __launch_bounds__(256) void fc_reduce_tanh(
    const float* __restrict__ PB, const float* __restrict__ bias,
    float* __restrict__ out, int Mrows, int rps, int c0) {
  constexpr int KS = 8;
  int idx = blockIdx.x * 256 + threadIdx.x;
  int m = idx >> 9, n = idx & 511;
  if (m >= Mrows) return;
  float s = bias[n];
#pragma unroll
  for (int ks = 0; ks < KS; ++ks)
    s += PB[((size_t)ks * Mrows + m) * 512 + n];
  int st = m / rps, rr = m - st * rps;
  out[((size_t)st * 1024 + c0 + rr) * 512 + n] = tanhf(s);
}

extern "C" void kernel_launch(void* const* d_in, const int* in_sizes, int n_in,
                              void* d_out, int out_size, void* d_ws,
                              size_t ws_size, hipStream_t stream) {
  const float* x = (const float*)d_in[0];
  const float* enc0_w1 = (const float*)d_in[1];
  const float* enc0_b1 = (const float*)d_in[2];
  const float* enc0_w2 = (const float*)d_in[3];
  const float* enc0_b2 = (const float*)d_in[4];
  const float* enc0_ws = (const float*)d_in[5];
  const float* enc0_bs = (const float*)d_in[6];
  const float* enc_w = (const float*)d_in[7];
  const float* enc_b = (const float*)d_in[8];
  const float* dec_w = (const float*)d_in[9];
  const float* dec_b = (const float*)d_in[10];
  const float* fc1_w = (const float*)d_in[11];
  const float* fc1_b = (const float*)d_in[12];
  const float* means_s = (const float*)d_in[13];
  const float* means_n = (const float*)d_in[14];

  const size_t WB = 2285568;  // transposed-weight bytes
  int BC = 32;
  for (int c = 512; c >= 32; c >>= 1)
    if (WB + (size_t)c * 524288 <= ws_size) { BC = c; break; }

  double* wT0d = (double*)d_ws;
  double* wTed = wT0d + 36864;
  float* wTdf = (float*)(wTed + 221184);
  double* E0d = (double*)(wTdf + 55296);
  double* E1d = E0d + (size_t)BC * 32768;
  float* qs = (float*)E1d;
  float* qn = qs + (size_t)BC * 16384;
  float* D0 = qn + (size_t)BC * 16384;
  float* T1 = D0 + (size_t)BC * 16384;
  float* Dz = (float*)E0d;                    // 2*BC*16384 floats
  float* PB = Dz + (size_t)2 * BC * 16384;    // 8*2*BC*512 floats
  float* out = (float*)d_out;

  transpose_w_f64_kernel<<<dim3(144), 256, 0, stream>>>(enc0_w2, wT0d, 64, 1);
  transpose_w_f64_kernel<<<dim3(864), 256, 0, stream>>>(enc_w, wTed, 64, 6);
  transpose_w_f32_kernel<<<dim3(216), 256, 0, stream>>>(dec_w, wTdf, 32, 6);

  for (int c0 = 0; c0 < BATCH; c0 += BC) {
    const float* xb = x + (size_t)c0 * TB;

    // encoder (f64)
    enc0_f64_kernel<<<dim3(8, BC), 256, 0, stream>>>(
        xb, enc0_w1, enc0_b1, wT0d, enc0_b2, enc0_ws, enc0_bs, E0d);
    for (int i = 0; i < 3; ++i) {
      conv64_f64_kernel<false><<<dim3(8, BC), 256, 0, stream>>>(
          E0d, wTed + (2 * i) * 36864, enc_b + (2 * i) * 64, nullptr, E1d);
      conv64_f64_kernel<true><<<dim3(8, BC), 256, 0, stream>>>(
          E1d, wTed + (2 * i + 1) * 36864, enc_b + (2 * i + 1) * 64, E0d, E0d);
    }

    // vector-quantize (writes idx outputs directly)
    code_assign_kernel<64><<<dim3(2, BC), 256, 0, stream>>>(
        E0d, 0, means_s, qs, out + 2 * 524288 + (size_t)c0 * TB);
    code_assign_kernel<32><<<dim3(2, BC), 256, 0, stream>>>(
        E0d, 32, means_n, qn, out + 3 * 524288 + (size_t)c0 * TB);

    // decoders; final z for stream s -> Dz rows [0,BC), n -> rows [BC,2BC)
    float* destS = Dz;
    float* destN = Dz + (size_t)BC * 16384;
    {
      float* outs[3] = {T1, qs, destS};
      const float* zin = qs;
      for (int i = 0; i < 3; ++i) {
        conv32_f32_kernel<false><<<dim3(4, BC), 256, 0, stream>>>(
            zin, wTdf + (2 * i) * 9216, dec_b + (2 * i) * 32, nullptr, D0);
        conv32_f32_kernel<true><<<dim3(4, BC), 256, 0, stream>>>(
            D0, wTdf + (2 * i + 1) * 9216, dec_b + (2 * i + 1) * 32, zin,
            outs[i]);
        zin = outs[i];
      }
    }
    {
      float* outs[3] = {T1, qn, destN};
      const float* zin = qn;
      for (int i = 0; i < 3; ++i) {
        conv32_f32_kernel<false><<<dim3(4, BC), 256, 0, stream>>>(
            zin, wTdf + (2 * i) * 9216, dec_b + (2 * i) * 32, nullptr, D0);
        conv32_f32_kernel<true><<<dim3(4, BC), 256, 0, stream>>>(
            D0, wTdf + (2 * i + 1) * 9216, dec_b + (2 * i + 1) * 32, zin,
            outs[i]);
        zin = outs[i];
      }
    }

    // FC: split-K partials + reduce
    fc_partial_gemm<<<dim3(8, (2 * BC) / 64, 8), 256, 0, stream>>>(
        Dz, fc1_w, PB, 2 * BC);
    fc_reduce_tanh<<<dim3((2 * BC * 512) / 256), 256, 0, stream>>>(
        PB, fc1_b, out, 2 * BC, BC, c0);
  }
}

// Round 10
// 8356.015 us; speedup vs baseline: 1.9262x; 1.0065x over previous
//
#include <hip/hip_runtime.h>
#include <math.h>

// ---------------------------------------------------------------------------
// AE_control: B=1024, T=512, D=64, K=9, NUM_M=64, NUM_N=32, SCALE=1
// Encoder + argmin in f64 (idx needs exact argmin vs f64 np reference;
// accumulation order MUST stay cin-major, k-inner — proven rounds 5/8/9).
// R10: pin xw[24] into VGPRs via empty inline asm (b128 loads, one lgkm
// batch per cin) — LDS pipe was the conv64 limiter (~864cy reads vs 576cy FMA).
// Decoder + FC f32 (round-5 proven). BC=256.
// ---------------------------------------------------------------------------

#define TB 512
#define BATCH 1024

// (nmat, C, C, 9) f32 -> (nmat, 9, C, C) f64  [k][cin][cout]
__global__ __launch_bounds__(256) void transpose_w_f64_kernel(
    const float* __restrict__ w, double* __restrict__ wT, int C, int nmat) {
  int total = nmat * C * C * 9;
  for (int i = blockIdx.x * blockDim.x + threadIdx.x; i < total;
       i += gridDim.x * blockDim.x) {
    int mat = i / (C * C * 9);
    int r = i % (C * C * 9);
    int cout = r / (C * 9);
    int rem = r % (C * 9);
    int cin = rem / 9;
    int k = rem % 9;
    wT[mat * C * C * 9 + (k * C + cin) * C + cout] = (double)w[i];
  }
}

// (nmat, C, C, 9) f32 -> (nmat, 9, C, C) f32
__global__ __launch_bounds__(256) void transpose_w_f32_kernel(
    const float* __restrict__ w, float* __restrict__ wT, int C, int nmat) {
  int total = nmat * C * C * 9;
  for (int i = blockIdx.x * blockDim.x + threadIdx.x; i < total;
       i += gridDim.x * blockDim.x) {
    int mat = i / (C * C * 9);
    int r = i % (C * C * 9);
    int cout = r / (C * 9);
    int rem = r % (C * 9);
    int cin = rem / 9;
    int k = rem % 9;
    wT[mat * C * C * 9 + (k * C + cin) * C + cout] = w[i];
  }
}

// Core f64 conv body: lane = cout (64 lanes), wave = t-slab (16 t each).
// src: LDS [64][72] (tt=0 <-> t0-4). wT: global [k][cin][cout] (per-lane
// coalesced loads). acc[t] accumulates cin-major, k-inner (argmin-safe order).
// xw pinned in VGPRs (inline-asm keep-live) so LDS is read once per cin.
__device__ __forceinline__ void conv64_body(const double* __restrict__ xs,
                                            const double* __restrict__ wT,
                                            double acc[16], int lane,
                                            int wslab) {
  double w[9];
  {
    const double* wp = wT + lane;  // cin = 0
#pragma unroll
    for (int k = 0; k < 9; ++k) w[k] = wp[k * 4096];
  }
  for (int cin = 0; cin < 64; ++cin) {
    const double* xr = xs + cin * 72 + wslab * 16;
    double xw[24];
#pragma unroll
    for (int i = 0; i < 24; i += 2) {
      double2 v = *(const double2*)&xr[i];  // ds_read_b128
      xw[i] = v.x;
      xw[i + 1] = v.y;
    }
#pragma unroll
    for (int i = 0; i < 24; ++i) asm volatile("" : "+v"(xw[i]));  // pin VGPR
    double wc[9];
#pragma unroll
    for (int k = 0; k < 9; ++k) wc[k] = w[k];
    if (cin + 1 < 64) {
      const double* wpn = wT + (cin + 1) * 64 + lane;
#pragma unroll
      for (int k = 0; k < 9; ++k) w[k] = wpn[k * 4096];  // prefetch next cin
    }
#pragma unroll
    for (int k = 0; k < 9; ++k) {
#pragma unroll
      for (int t = 0; t < 16; ++t) acc[t] = fma(wc[k], xw[t + k], acc[t]);
    }
  }
}

// enc0 fused block (f64): x f32 (BC,512) -> out f64 (BC,64,512)
__global__ __launch_bounds__(256, 1) void enc0_f64_kernel(
    const float* __restrict__ x, const float* __restrict__ w1,
    const float* __restrict__ b1, const double* __restrict__ w2T,
    const float* __restrict__ b2, const float* __restrict__ wsc,
    const float* __restrict__ bsc, double* __restrict__ out) {
  __shared__ double xs0[80];
  __shared__ double w1s[576];
  __shared__ double b1s[64];
  __shared__ double mid[64 * 72];
  int b = blockIdx.y;
  int t0 = blockIdx.x * 64;
  int tid = threadIdx.x;
  if (tid < 80) {
    int t = t0 - 8 + tid;
    xs0[tid] = (t >= 0 && t < TB) ? (double)x[b * TB + t] : 0.0;
  }
  for (int i = tid; i < 576; i += 256) w1s[i] = (double)w1[i];
  if (tid < 64) b1s[tid] = (double)b1[tid];
  __syncthreads();
  // mid[cout][tt], tt in [0,72): t = t0-4+tt ; zero outside [0,TB) (SAME pad)
  for (int e = tid; e < 64 * 72; e += 256) {
    int cout = e / 72, tt = e % 72;
    int t = t0 - 4 + tt;
    double acc = b1s[cout];
#pragma unroll
    for (int k = 0; k < 9; ++k) acc = fma(w1s[cout * 9 + k], xs0[tt + k], acc);
    mid[e] = (t >= 0 && t < TB) ? fmax(acc, 0.0) : 0.0;
  }
  __syncthreads();
  int wave = tid >> 6;
  int lane = tid & 63;
  double acc[16];
  double bz = (double)b2[lane];
#pragma unroll
  for (int t = 0; t < 16; ++t) acc[t] = bz;
  conv64_body(mid, w2T, acc, lane, wave);
  __syncthreads();  // mid reads done; reuse as transpose buffer [64][65]
  double* T = mid;
#pragma unroll
  for (int t = 0; t < 16; ++t) T[lane * 65 + wave * 16 + t] = acc[t];
  __syncthreads();
  for (int i = tid; i < 4096; i += 256) {
    int cout = i >> 6, tt = i & 63;
    double v = T[cout * 65 + tt] +
               fma((double)wsc[cout], xs0[8 + tt], (double)bsc[cout]);
    out[(b * 64 + cout) * TB + t0 + tt] = fmax(v, 0.0);
  }
}

// f64 conv 64->64, K=9, SAME. out = relu(conv(in)+bias [+ skip])
template <bool SKIP>
__global__ __launch_bounds__(256, 1) void conv64_f64_kernel(
    const double* __restrict__ in, const double* __restrict__ wT,
    const float* __restrict__ bias, const double* __restrict__ skip,
    double* __restrict__ out) {
  __shared__ double xs[64 * 72];
  int b = blockIdx.y;
  int t0 = blockIdx.x * 64;
  int tid = threadIdx.x;
  for (int i = tid; i < 64 * 72; i += 256) {
    int cin = i / 72, tt = i % 72;
    int t = t0 - 4 + tt;
    xs[i] = (t >= 0 && t < TB) ? in[(b * 64 + cin) * TB + t] : 0.0;
  }
  __syncthreads();
  int wave = tid >> 6;
  int lane = tid & 63;
  double acc[16];
  double bz = (double)bias[lane];
#pragma unroll
  for (int t = 0; t < 16; ++t) acc[t] = bz;
  conv64_body(xs, wT, acc, lane, wave);
  __syncthreads();  // xs reads done; reuse as transpose buffer [64][65]
  double* T = xs;
#pragma unroll
  for (int t = 0; t < 16; ++t) T[lane * 65 + wave * 16 + t] = acc[t];
  __syncthreads();
  for (int i = tid; i < 4096; i += 256) {
    int cout = i >> 6, tt = i & 63;
    double v = T[cout * 65 + tt];
    if constexpr (SKIP) v += skip[(b * 64 + cout) * TB + t0 + tt];
    out[(b * 64 + cout) * TB + t0 + tt] = fmax(v, 0.0);
  }
}

// f32 conv 32->32 (decoder), K=9, SAME  [round-5 proven form]
template <bool SKIP>
__global__ __launch_bounds__(256) void conv32_f32_kernel(
    const float* __restrict__ in, const float* __restrict__ wT,
    const float* __restrict__ bias, const float* __restrict__ skip,
    float* __restrict__ out) {
  constexpr int XW = 136;
  __shared__ float xs[32 * XW];
  int b = blockIdx.y;
  int t0 = blockIdx.x * 128;
  int tid = threadIdx.x;
  for (int i = tid; i < 32 * XW; i += 256) {
    int cin = i / XW, tt = i % XW;
    int t = t0 - 4 + tt;
    xs[i] = (t >= 0 && t < TB) ? in[(b * 32 + cin) * TB + t] : 0.f;
  }
  __syncthreads();
  int wave = __builtin_amdgcn_readfirstlane(tid >> 6);
  int lane = tid & 63;
  int cbase = (wave & 1) * 16;
  int ttl = (wave >> 1) * 64 + lane;
  float acc[16];
#pragma unroll
  for (int j = 0; j < 16; ++j) acc[j] = bias[cbase + j];
  for (int cin = 0; cin < 32; ++cin) {
#pragma unroll
    for (int k = 0; k < 9; ++k) {
      float xv = xs[cin * XW + ttl + k];
      const float* wp = wT + (k * 32 + cin) * 32 + cbase;
#pragma unroll
      for (int j = 0; j < 16; ++j) acc[j] = fmaf(xv, wp[j], acc[j]);
    }
  }
  int t = t0 + ttl;
#pragma unroll
  for (int j = 0; j < 16; ++j) {
    float v = acc[j];
    if constexpr (SKIP) v += skip[(b * 32 + cbase + j) * TB + t];
    out[(b * 32 + cbase + j) * TB + t] = fmaxf(v, 0.f);
  }
}

// code_assign (f64 distances/argmin, f32 q)
template <int M>
__global__ __launch_bounds__(256) void code_assign_kernel(
    const double* __restrict__ h, int coff, const float* __restrict__ means,
    float* __restrict__ q, float* __restrict__ idx_out) {
  __shared__ double ms[32 * M];
  __shared__ float msf[32 * M];
  __shared__ double msq[M];
  int b = blockIdx.y;
  int tid = threadIdx.x;
  int t = blockIdx.x * 256 + tid;
  for (int i = tid; i < 32 * M; i += 256) {
    float v = means[i];
    ms[i] = (double)v;
    msf[i] = v;
  }
  __syncthreads();
  if (tid < M) {
    double s = 0.0;
#pragma unroll
    for (int c = 0; c < 32; ++c) s = fma(ms[c * M + tid], ms[c * M + tid], s);
    msq[tid] = s;
  }
  __syncthreads();
  double xv[32];
  double sx = 0.0;
#pragma unroll
  for (int c = 0; c < 32; ++c) {
    xv[c] = h[(b * 64 + coff + c) * TB + t];
    sx = fma(xv[c], xv[c], sx);
  }
  double dmin = 1e300;
  int imin = 0;
  float ssum = 0.f;
  float qv[32];
#pragma unroll
  for (int c = 0; c < 32; ++c) qv[c] = 0.f;
  for (int m = 0; m < M; ++m) {
    double dot = 0.0;
#pragma unroll
    for (int c = 0; c < 32; ++c) dot = fma(xv[c], ms[c * M + m], dot);
    double d = sx - 2.0 * dot + msq[m];
    float p;
    if (d < dmin) {
      float f = expf((float)(d - dmin));
      ssum *= f;
#pragma unroll
      for (int c = 0; c < 32; ++c) qv[c] *= f;
      dmin = d;
      imin = m;
      p = 1.f;
    } else {
      p = expf((float)(dmin - d));
    }
    ssum += p;
#pragma unroll
    for (int c = 0; c < 32; ++c) qv[c] = fmaf(p, msf[c * M + m], qv[c]);
  }
  float inv = 1.f / ssum;
#pragma unroll
  for (int c = 0; c < 32; ++c) q[(b * 32 + c) * TB + t] = qv[c] * inv;
  idx_out[b * TB + t] = (float)imin;
}

// Split-K FC partial: Z [Mrows][16384], w [512][16384].
__global__ __launch_bounds__(256) void fc_partial_gemm(
    const float* __restrict__ Z, const float* __restrict__ w,
    float* __restrict__ PB, int Mrows) {
  constexpr int BK = 32;
  constexpr int KC = 2048;
  __shared__ float As[BK][68];
  __shared__ float Bs[BK][68];
  int m0 = blockIdx.y * 64;
  int n0 = blockIdx.x * 64;
  int kbase = blockIdx.z * KC;
  int tid = threadIdx.x;
  int row = tid >> 2;
  int kq = (tid & 3) * 4;
  const float* zrow = Z + (size_t)(m0 + row) * 16384 + kbase;
  const float* wrow = w + (size_t)(n0 + row) * 16384 + kbase;
  int mg = tid >> 4;
  int ng = tid & 15;
  float acc[4][4] = {};
  for (int k0 = 0; k0 < KC; k0 += BK) {
    float4 a0 = *(const float4*)&zrow[k0 + kq];
    float4 a1 = *(const float4*)&zrow[k0 + kq + 16];
    float4 b0 = *(const float4*)&wrow[k0 + kq];
    float4 b1 = *(const float4*)&wrow[k0 + kq + 16];
    __syncthreads();
    As[kq + 0][row] = a0.x; As[kq + 1][row] = a0.y;
    As[kq + 2][row] = a0.z; As[kq + 3][row] = a0.w;
    As[kq + 16][row] = a1.x; As[kq + 17][row] = a1.y;
    As[kq + 18][row] = a1.z; As[kq + 19][row] = a1.w;
    Bs[kq + 0][row] = b0.x; Bs[kq + 1][row] = b0.y;
    Bs[kq + 2][row] = b0.z; Bs[kq + 3][row] = b0.w;
    Bs[kq + 16][row] = b1.x; Bs[kq + 17][row] = b1.y;
    Bs[kq + 18][row] = b1.z; Bs[kq + 19][row] = b1.w;
    __syncthreads();
#pragma unroll
    for (int kk = 0; kk < BK; ++kk) {
      float4 av = *(const float4*)&As[kk][mg * 4];
      float4 bv = *(const float4*)&Bs[kk][ng * 4];
      acc[0][0] = fmaf(av.x, bv.x, acc[0][0]);
      acc[0][1] = fmaf(av.x, bv.y, acc[0][1]);
      acc[0][2] = fmaf(av.x, bv.z, acc[0][2]);
      acc[0][3] = fmaf(av.x, bv.w, acc[0][3]);
      acc[1][0] = fmaf(av.y, bv.x, acc[1][0]);
      acc[1][1] = fmaf(av.y, bv.y, acc[1][1]);
      acc[1][2] = fmaf(av.y, bv.z, acc[1][2]);
      acc[1][3] = fmaf(av.y, bv.w, acc[1][3]);
      acc[2][0] = fmaf(av.z, bv.x, acc[2][0]);
      acc[2][1] = fmaf(av.z, bv.y, acc[2][1]);
      acc[2][2] = fmaf(av.z, bv.z, acc[2][2]);
      acc[2][3] = fmaf(av.z, bv.w, acc[2][3]);
      acc[3][0] = fmaf(av.w, bv.x, acc[3][0]);
      acc[3][1] = fmaf(av.w, bv.y, acc[3][1]);
      acc[3][2] = fmaf(av.w, bv.z, acc[3][2]);
      acc[3][3] = fmaf(av.w, bv.w, acc[3][3]);
    }
  }
  float* pbase = PB + (size_t)blockIdx.z * Mrows * 512;
#pragma unroll
  for (int mi = 0; mi < 4; ++mi) {
    float4 v = {acc[mi][0], acc[mi][1], acc[mi][2], acc[mi][3]};
    *(float4*)&pbase[(size_t)(m0 + mg * 4 + mi) * 512 + n0 + ng * 4] = v;
  }
}

// Reduce KS partials + bias + tanh -> out rows (stacked streams)
__global__ __launch_bounds__(256) void fc_reduce_tanh(
    const float* __restrict__ PB, const float* __restrict__ bias,
    float* __restrict__ out, int Mrows, int rps, int c0) {
  constexpr int KS = 8;
  int idx = blockIdx.x * 256 + threadIdx.x;
  int m = idx >> 9, n = idx & 511;
  if (m >= Mrows) return;
  float s = bias[n];
#pragma unroll
  for (int ks = 0; ks < KS; ++ks)
    s += PB[((size_t)ks * Mrows + m) * 512 + n];
  int st = m / rps, rr = m - st * rps;
  out[((size_t)st * 1024 + c0 + rr) * 512 + n] = tanhf(s);
}

extern "C" void kernel_launch(void* const* d_in, const int* in_sizes, int n_in,
                              void* d_out, int out_size, void* d_ws,
                              size_t ws_size, hipStream_t stream) {
  const float* x = (const float*)d_in[0];
  const float* enc0_w1 = (const float*)d_in[1];
  const float* enc0_b1 = (const float*)d_in[2];
  const float* enc0_w2 = (const float*)d_in[3];
  const float* enc0_b2 = (const float*)d_in[4];
  const float* enc0_ws = (const float*)d_in[5];
  const float* enc0_bs = (const float*)d_in[6];
  const float* enc_w = (const float*)d_in[7];
  const float* enc_b = (const float*)d_in[8];
  const float* dec_w = (const float*)d_in[9];
  const float* dec_b = (const float*)d_in[10];
  const float* fc1_w = (const float*)d_in[11];
  const float* fc1_b = (const float*)d_in[12];
  const float* means_s = (const float*)d_in[13];
  const float* means_n = (const float*)d_in[14];

  const size_t WB = 2285568;  // transposed-weight bytes
  int BC = 32;
  for (int c = 512; c >= 32; c >>= 1)
    if (WB + (size_t)c * 524288 <= ws_size) { BC = c; break; }

  double* wT0d = (double*)d_ws;
  double* wTed = wT0d + 36864;
  float* wTdf = (float*)(wTed + 221184);
  double* E0d = (double*)(wTdf + 55296);
  double* E1d = E0d + (size_t)BC * 32768;
  float* qs = (float*)E1d;
  float* qn = qs + (size_t)BC * 16384;
  float* D0 = qn + (size_t)BC * 16384;
  float* T1 = D0 + (size_t)BC * 16384;
  float* Dz = (float*)E0d;                    // 2*BC*16384 floats
  float* PB = Dz + (size_t)2 * BC * 16384;    // 8*2*BC*512 floats
  float* out = (float*)d_out;

  transpose_w_f64_kernel<<<dim3(144), 256, 0, stream>>>(enc0_w2, wT0d, 64, 1);
  transpose_w_f64_kernel<<<dim3(864), 256, 0, stream>>>(enc_w, wTed, 64, 6);
  transpose_w_f32_kernel<<<dim3(216), 256, 0, stream>>>(dec_w, wTdf, 32, 6);

  for (int c0 = 0; c0 < BATCH; c0 += BC) {
    const float* xb = x + (size_t)c0 * TB;

    // encoder (f64)
    enc0_f64_kernel<<<dim3(8, BC), 256, 0, stream>>>(
        xb, enc0_w1, enc0_b1, wT0d, enc0_b2, enc0_ws, enc0_bs, E0d);
    for (int i = 0; i < 3; ++i) {
      conv64_f64_kernel<false><<<dim3(8, BC), 256, 0, stream>>>(
          E0d, wTed + (2 * i) * 36864, enc_b + (2 * i) * 64, nullptr, E1d);
      conv64_f64_kernel<true><<<dim3(8, BC), 256, 0, stream>>>(
          E1d, wTed + (2 * i + 1) * 36864, enc_b + (2 * i + 1) * 64, E0d, E0d);
    }

    // vector-quantize (writes idx outputs directly)
    code_assign_kernel<64><<<dim3(2, BC), 256, 0, stream>>>(
        E0d, 0, means_s, qs, out + 2 * 524288 + (size_t)c0 * TB);
    code_assign_kernel<32><<<dim3(2, BC), 256, 0, stream>>>(
        E0d, 32, means_n, qn, out + 3 * 524288 + (size_t)c0 * TB);

    // decoders; final z for stream s -> Dz rows [0,BC), n -> rows [BC,2BC)
    float* destS = Dz;
    float* destN = Dz + (size_t)BC * 16384;
    {
      float* outs[3] = {T1, qs, destS};
      const float* zin = qs;
      for (int i = 0; i < 3; ++i) {
        conv32_f32_kernel<false><<<dim3(4, BC), 256, 0, stream>>>(
            zin, wTdf + (2 * i) * 9216, dec_b + (2 * i) * 32, nullptr, D0);
        conv32_f32_kernel<true><<<dim3(4, BC), 256, 0, stream>>>(
            D0, wTdf + (2 * i + 1) * 9216, dec_b + (2 * i + 1) * 32, zin,
            outs[i]);
        zin = outs[i];
      }
    }
    {
      float* outs[3] = {T1, qn, destN};
      const float* zin = qn;
      for (int i = 0; i < 3; ++i) {
        conv32_f32_kernel<false><<<dim3(4, BC), 256, 0, stream>>>(
            zin, wTdf + (2 * i) * 9216, dec_b + (2 * i) * 32, nullptr, D0);
        conv32_f32_kernel<true><<<dim3(4, BC), 256, 0, stream>>>(
            D0, wTdf + (2 * i + 1) * 9216, dec_b + (2 * i + 1) * 32, zin,
            outs[i]);
        zin = outs[i];
      }
    }

    // FC: split-K partials + reduce
    fc_partial_gemm<<<dim3(8, (2 * BC) / 64, 8), 256, 0, stream>>>(
        Dz, fc1_w, PB, 2 * BC);
    fc_reduce_tanh<<<dim3((2 * BC * 512) / 256), 256, 0, stream>>>(
        PB, fc1_b, out, 2 * BC, BC, c0);
  }
}

// Round 11
// 8198.736 us; speedup vs baseline: 1.9631x; 1.0192x over previous
//
#include <hip/hip_runtime.h>
#include <math.h>

// ---------------------------------------------------------------------------
// AE_control: B=1024, T=512, D=64, K=9, NUM_M=64, NUM_N=32, SCALE=1
// Encoder + argmin in f64 (idx needs exact argmin vs f64 np reference;
// per-chain accumulation order MUST stay cin-major, k-ascending).
// R11: conv64 body = load-and-consume streaming (12 b128/cin, single-use,
// no rematerialization), weights [cin][k][cout] double-buffered (no copies).
// Chain order bit-identical to rounds 5/8/9/10. Decoder + FC f32. BC=256.
// ---------------------------------------------------------------------------

#define TB 512
#define BATCH 1024

// (nmat, C, C, 9) f32 -> (nmat, C, 9, C) f64: wT2[cin][k][cout]
__global__ __launch_bounds__(256) void transpose_w2_f64_kernel(
    const float* __restrict__ w, double* __restrict__ wT, int C, int nmat) {
  int total = nmat * C * C * 9;
  for (int i = blockIdx.x * blockDim.x + threadIdx.x; i < total;
       i += gridDim.x * blockDim.x) {
    int mat = i / (C * C * 9);
    int r = i % (C * C * 9);
    int cout = r / (C * 9);
    int rem = r % (C * 9);
    int cin = rem / 9;
    int k = rem % 9;
    wT[((mat * C + cin) * 9 + k) * C + cout] = (double)w[i];
  }
}

// (nmat, C, C, 9) f32 -> (nmat, 9, C, C) f32  [k][cin][cout]
__global__ __launch_bounds__(256) void transpose_w_f32_kernel(
    const float* __restrict__ w, float* __restrict__ wT, int C, int nmat) {
  int total = nmat * C * C * 9;
  for (int i = blockIdx.x * blockDim.x + threadIdx.x; i < total;
       i += gridDim.x * blockDim.x) {
    int mat = i / (C * C * 9);
    int r = i % (C * C * 9);
    int cout = r / (C * 9);
    int rem = r % (C * 9);
    int cin = rem / 9;
    int k = rem % 9;
    wT[mat * C * C * 9 + (k * C + cin) * C + cout] = w[i];
  }
}

// Core f64 conv body: lane = cout (64 lanes), wave = t-slab (16 t each).
// src xs: LDS [64][72] (tt=0 <-> t0-4). wT2: global [cin][9][64].
// Streaming form: each x element loaded once (b128) and consumed immediately:
//   acc[j-k] += w[k]*x[j], j ascending  ==> per-chain k ascending (bit-exact
//   vs the k-inner form). Weights double-buffered wA/wB, no copies.
template <typename F>
__device__ __forceinline__ void conv64_fma_stream(const double* __restrict__ xr,
                                                  const double (&w)[9],
                                                  F&& upd) {
#pragma unroll
  for (int j2 = 0; j2 < 24; j2 += 2) {
    double2 v = *(const double2*)&xr[j2];
#pragma unroll
    for (int k = 0; k < 9; ++k) {
      int ta = j2 - k;
      if (ta >= 0 && ta < 16) upd(ta, w[k], v.x);
    }
#pragma unroll
    for (int k = 0; k < 9; ++k) {
      int tb = j2 + 1 - k;
      if (tb >= 0 && tb < 16) upd(tb, w[k], v.y);
    }
  }
}

__device__ __forceinline__ void conv64_body(const double* __restrict__ xs,
                                            const double* __restrict__ wT2,
                                            double acc[16], int lane,
                                            int wslab) {
  const double* wp0 = wT2 + lane;
  double wA[9], wB[9];
#pragma unroll
  for (int k = 0; k < 9; ++k) wA[k] = wp0[k * 64];
  const double* xb = xs + wslab * 16;
  auto upd = [&](int t, double w, double x) { acc[t] = fma(w, x, acc[t]); };
#pragma unroll 1
  for (int cin = 0; cin < 64; cin += 2) {
    {
      const double* wpn = wp0 + (cin + 1) * 576;
#pragma unroll
      for (int k = 0; k < 9; ++k) wB[k] = wpn[k * 64];
      conv64_fma_stream(xb + cin * 72, wA, upd);
    }
    {
      if (cin + 2 < 64) {
        const double* wpn = wp0 + (cin + 2) * 576;
#pragma unroll
        for (int k = 0; k < 9; ++k) wA[k] = wpn[k * 64];
      }
      conv64_fma_stream(xb + (cin + 1) * 72, wB, upd);
    }
  }
}

// enc0 fused block (f64): x f32 (BC,512) -> out f64 (BC,64,512)
__global__ __launch_bounds__(256, 1) void enc0_f64_kernel(
    const float* __restrict__ x, const float* __restrict__ w1,
    const float* __restrict__ b1, const double* __restrict__ w2T,
    const float* __restrict__ b2, const float* __restrict__ wsc,
    const float* __restrict__ bsc, double* __restrict__ out) {
  __shared__ double xs0[80];
  __shared__ double w1s[576];
  __shared__ double b1s[64];
  __shared__ double mid[64 * 72];
  int b = blockIdx.y;
  int t0 = blockIdx.x * 64;
  int tid = threadIdx.x;
  if (tid < 80) {
    int t = t0 - 8 + tid;
    xs0[tid] = (t >= 0 && t < TB) ? (double)x[b * TB + t] : 0.0;
  }
  for (int i = tid; i < 576; i += 256) w1s[i] = (double)w1[i];
  if (tid < 64) b1s[tid] = (double)b1[tid];
  __syncthreads();
  // mid[cout][tt], tt in [0,72): t = t0-4+tt ; zero outside [0,TB) (SAME pad)
  for (int e = tid; e < 64 * 72; e += 256) {
    int cout = e / 72, tt = e % 72;
    int t = t0 - 4 + tt;
    double acc = b1s[cout];
#pragma unroll
    for (int k = 0; k < 9; ++k) acc = fma(w1s[cout * 9 + k], xs0[tt + k], acc);
    mid[e] = (t >= 0 && t < TB) ? fmax(acc, 0.0) : 0.0;
  }
  __syncthreads();
  int wave = tid >> 6;
  int lane = tid & 63;
  double acc[16];
  double bz = (double)b2[lane];
#pragma unroll
  for (int t = 0; t < 16; ++t) acc[t] = bz;
  conv64_body(mid, w2T, acc, lane, wave);
  __syncthreads();  // mid reads done; reuse as transpose buffer [64][65]
  double* T = mid;
#pragma unroll
  for (int t = 0; t < 16; ++t) T[lane * 65 + wave * 16 + t] = acc[t];
  __syncthreads();
  for (int i = tid; i < 4096; i += 256) {
    int cout = i >> 6, tt = i & 63;
    double v = T[cout * 65 + tt] +
               fma((double)wsc[cout], xs0[8 + tt], (double)bsc[cout]);
    out[(b * 64 + cout) * TB + t0 + tt] = fmax(v, 0.0);
  }
}

// f64 conv 64->64, K=9, SAME. out = relu(conv(in)+bias [+ skip])
template <bool SKIP>
__global__ __launch_bounds__(256, 1) void conv64_f64_kernel(
    const double* __restrict__ in, const double* __restrict__ wT2,
    const float* __restrict__ bias, const double* __restrict__ skip,
    double* __restrict__ out) {
  __shared__ double xs[64 * 72];
  int b = blockIdx.y;
  int t0 = blockIdx.x * 64;
  int tid = threadIdx.x;
  for (int i = tid; i < 64 * 72; i += 256) {
    int cin = i / 72, tt = i % 72;
    int t = t0 - 4 + tt;
    xs[i] = (t >= 0 && t < TB) ? in[(b * 64 + cin) * TB + t] : 0.0;
  }
  __syncthreads();
  int wave = tid >> 6;
  int lane = tid & 63;
  double acc[16];
  double bz = (double)bias[lane];
#pragma unroll
  for (int t = 0; t < 16; ++t) acc[t] = bz;
  conv64_body(xs, wT2, acc, lane, wave);
  __syncthreads();  // xs reads done; reuse as transpose buffer [64][65]
  double* T = xs;
#pragma unroll
  for (int t = 0; t < 16; ++t) T[lane * 65 + wave * 16 + t] = acc[t];
  __syncthreads();
  for (int i = tid; i < 4096; i += 256) {
    int cout = i >> 6, tt = i & 63;
    double v = T[cout * 65 + tt];
    if constexpr (SKIP) v += skip[(b * 64 + cout) * TB + t0 + tt];
    out[(b * 64 + cout) * TB + t0 + tt] = fmax(v, 0.0);
  }
}

// f32 conv 32->32 (decoder), K=9, SAME  [round-5 proven form]
template <bool SKIP>
__global__ __launch_bounds__(256) void conv32_f32_kernel(
    const float* __restrict__ in, const float* __restrict__ wT,
    const float* __restrict__ bias, const float* __restrict__ skip,
    float* __restrict__ out) {
  constexpr int XW = 136;
  __shared__ float xs[32 * XW];
  int b = blockIdx.y;
  int t0 = blockIdx.x * 128;
  int tid = threadIdx.x;
  for (int i = tid; i < 32 * XW; i += 256) {
    int cin = i / XW, tt = i % XW;
    int t = t0 - 4 + tt;
    xs[i] = (t >= 0 && t < TB) ? in[(b * 32 + cin) * TB + t] : 0.f;
  }
  __syncthreads();
  int wave = __builtin_amdgcn_readfirstlane(tid >> 6);
  int lane = tid & 63;
  int cbase = (wave & 1) * 16;
  int ttl = (wave >> 1) * 64 + lane;
  float acc[16];
#pragma unroll
  for (int j = 0; j < 16; ++j) acc[j] = bias[cbase + j];
  for (int cin = 0; cin < 32; ++cin) {
#pragma unroll
    for (int k = 0; k < 9; ++k) {
      float xv = xs[cin * XW + ttl + k];
      const float* wp = wT + (k * 32 + cin) * 32 + cbase;
#pragma unroll
      for (int j = 0; j < 16; ++j) acc[j] = fmaf(xv, wp[j], acc[j]);
    }
  }
  int t = t0 + ttl;
#pragma unroll
  for (int j = 0; j < 16; ++j) {
    float v = acc[j];
    if constexpr (SKIP) v += skip[(b * 32 + cbase + j) * TB + t];
    out[(b * 32 + cbase + j) * TB + t] = fmaxf(v, 0.f);
  }
}

// code_assign (f64 distances/argmin, f32 q)
template <int M>
__global__ __launch_bounds__(256) void code_assign_kernel(
    const double* __restrict__ h, int coff, const float* __restrict__ means,
    float* __restrict__ q, float* __restrict__ idx_out) {
  __shared__ double ms[32 * M];
  __shared__ float msf[32 * M];
  __shared__ double msq[M];
  int b = blockIdx.y;
  int tid = threadIdx.x;
  int t = blockIdx.x * 256 + tid;
  for (int i = tid; i < 32 * M; i += 256) {
    float v = means[i];
    ms[i] = (double)v;
    msf[i] = v;
  }
  __syncthreads();
  if (tid < M) {
    double s = 0.0;
#pragma unroll
    for (int c = 0; c < 32; ++c) s = fma(ms[c * M + tid], ms[c * M + tid], s);
    msq[tid] = s;
  }
  __syncthreads();
  double xv[32];
  double sx = 0.0;
#pragma unroll
  for (int c = 0; c < 32; ++c) {
    xv[c] = h[(b * 64 + coff + c) * TB + t];
    sx = fma(xv[c], xv[c], sx);
  }
  double dmin = 1e300;
  int imin = 0;
  float ssum = 0.f;
  float qv[32];
#pragma unroll
  for (int c = 0; c < 32; ++c) qv[c] = 0.f;
  for (int m = 0; m < M; ++m) {
    double dot = 0.0;
#pragma unroll
    for (int c = 0; c < 32; ++c) dot = fma(xv[c], ms[c * M + m], dot);
    double d = sx - 2.0 * dot + msq[m];
    float p;
    if (d < dmin) {
      float f = expf((float)(d - dmin));
      ssum *= f;
#pragma unroll
      for (int c = 0; c < 32; ++c) qv[c] *= f;
      dmin = d;
      imin = m;
      p = 1.f;
    } else {
      p = expf((float)(dmin - d));
    }
    ssum += p;
#pragma unroll
    for (int c = 0; c < 32; ++c) qv[c] = fmaf(p, msf[c * M + m], qv[c]);
  }
  float inv = 1.f / ssum;
#pragma unroll
  for (int c = 0; c < 32; ++c) q[(b * 32 + c) * TB + t] = qv[c] * inv;
  idx_out[b * TB + t] = (float)imin;
}

// Split-K FC partial: Z [Mrows][16384], w [512][16384].
__global__ __launch_bounds__(256) void fc_partial_gemm(
    const float* __restrict__ Z, const float* __restrict__ w,
    float* __restrict__ PB, int Mrows) {
  constexpr int BK = 32;
  constexpr int KC = 2048;
  __shared__ float As[BK][68];
  __shared__ float Bs[BK][68];
  int m0 = blockIdx.y * 64;
  int n0 = blockIdx.x * 64;
  int kbase = blockIdx.z * KC;
  int tid = threadIdx.x;
  int row = tid >> 2;
  int kq = (tid & 3) * 4;
  const float* zrow = Z + (size_t)(m0 + row) * 16384 + kbase;
  const float* wrow = w + (size_t)(n0 + row) * 16384 + kbase;
  int mg = tid >> 4;
  int ng = tid & 15;
  float acc[4][4] = {};
  for (int k0 = 0; k0 < KC; k0 += BK) {
    float4 a0 = *(const float4*)&zrow[k0 + kq];
    float4 a1 = *(const float4*)&zrow[k0 + kq + 16];
    float4 b0 = *(const float4*)&wrow[k0 + kq];
    float4 b1 = *(const float4*)&wrow[k0 + kq + 16];
    __syncthreads();
    As[kq + 0][row] = a0.x; As[kq + 1][row] = a0.y;
    As[kq + 2][row] = a0.z; As[kq + 3][row] = a0.w;
    As[kq + 16][row] = a1.x; As[kq + 17][row] = a1.y;
    As[kq + 18][row] = a1.z; As[kq + 19][row] = a1.w;
    Bs[kq + 0][row] = b0.x; Bs[kq + 1][row] = b0.y;
    Bs[kq + 2][row] = b0.z; Bs[kq + 3][row] = b0.w;
    Bs[kq + 16][row] = b1.x; Bs[kq + 17][row] = b1.y;
    Bs[kq + 18][row] = b1.z; Bs[kq + 19][row] = b1.w;
    __syncthreads();
#pragma unroll
    for (int kk = 0; kk < BK; ++kk) {
      float4 av = *(const float4*)&As[kk][mg * 4];
      float4 bv = *(const float4*)&Bs[kk][ng * 4];
      acc[0][0] = fmaf(av.x, bv.x, acc[0][0]);
      acc[0][1] = fmaf(av.x, bv.y, acc[0][1]);
      acc[0][2] = fmaf(av.x, bv.z, acc[0][2]);
      acc[0][3] = fmaf(av.x, bv.w, acc[0][3]);
      acc[1][0] = fmaf(av.y, bv.x, acc[1][0]);
      acc[1][1] = fmaf(av.y, bv.y, acc[1][1]);
      acc[1][2] = fmaf(av.y, bv.z, acc[1][2]);
      acc[1][3] = fmaf(av.y, bv.w, acc[1][3]);
      acc[2][0] = fmaf(av.z, bv.x, acc[2][0]);
      acc[2][1] = fmaf(av.z, bv.y, acc[2][1]);
      acc[2][2] = fmaf(av.z, bv.z, acc[2][2]);
      acc[2][3] = fmaf(av.z, bv.w, acc[2][3]);
      acc[3][0] = fmaf(av.w, bv.x, acc[3][0]);
      acc[3][1] = fmaf(av.w, bv.y, acc[3][1]);
      acc[3][2] = fmaf(av.w, bv.z, acc[3][2]);
      acc[3][3] = fmaf(av.w, bv.w, acc[3][3]);
    }
  }
  float* pbase = PB + (size_t)blockIdx.z * Mrows * 512;
#pragma unroll
  for (int mi = 0; mi < 4; ++mi) {
    float4 v = {acc[mi][0], acc[mi][1], acc[mi][2], acc[mi][3]};
    *(float4*)&pbase[(size_t)(m0 + mg * 4 + mi) * 512 + n0 + ng * 4] = v;
  }
}

// Reduce KS partials + bias + tanh -> out rows (stacked streams)
__global__ __launch_bounds__(256) void fc_reduce_tanh(
    const float* __restrict__ PB, const float* __restrict__ bias,
    float* __restrict__ out, int Mrows, int rps, int c0) {
  constexpr int KS = 8;
  int idx = blockIdx.x * 256 + threadIdx.x;
  int m = idx >> 9, n = idx & 511;
  if (m >= Mrows) return;
  float s = bias[n];
#pragma unroll
  for (int ks = 0; ks < KS; ++ks)
    s += PB[((size_t)ks * Mrows + m) * 512 + n];
  int st = m / rps, rr = m - st * rps;
  out[((size_t)st * 1024 + c0 + rr) * 512 + n] = tanhf(s);
}

extern "C" void kernel_launch(void* const* d_in, const int* in_sizes, int n_in,
                              void* d_out, int out_size, void* d_ws,
                              size_t ws_size, hipStream_t stream) {
  const float* x = (const float*)d_in[0];
  const float* enc0_w1 = (const float*)d_in[1];
  const float* enc0_b1 = (const float*)d_in[2];
  const float* enc0_w2 = (const float*)d_in[3];
  const float* enc0_b2 = (const float*)d_in[4];
  const float* enc0_ws = (const float*)d_in[5];
  const float* enc0_bs = (const float*)d_in[6];
  const float* enc_w = (const float*)d_in[7];
  const float* enc_b = (const float*)d_in[8];
  const float* dec_w = (const float*)d_in[9];
  const float* dec_b = (const float*)d_in[10];
  const float* fc1_w = (const float*)d_in[11];
  const float* fc1_b = (const float*)d_in[12];
  const float* means_s = (const float*)d_in[13];
  const float* means_n = (const float*)d_in[14];

  const size_t WB = 2285568;  // transposed-weight bytes
  int BC = 32;
  for (int c = 512; c >= 32; c >>= 1)
    if (WB + (size_t)c * 524288 <= ws_size) { BC = c; break; }

  double* wT0d = (double*)d_ws;
  double* wTed = wT0d + 36864;
  float* wTdf = (float*)(wTed + 221184);
  double* E0d = (double*)(wTdf + 55296);
  double* E1d = E0d + (size_t)BC * 32768;
  float* qs = (float*)E1d;
  float* qn = qs + (size_t)BC * 16384;
  float* D0 = qn + (size_t)BC * 16384;
  float* T1 = D0 + (size_t)BC * 16384;
  float* Dz = (float*)E0d;                    // 2*BC*16384 floats
  float* PB = Dz + (size_t)2 * BC * 16384;    // 8*2*BC*512 floats
  float* out = (float*)d_out;

  transpose_w2_f64_kernel<<<dim3(144), 256, 0, stream>>>(enc0_w2, wT0d, 64, 1);
  transpose_w2_f64_kernel<<<dim3(864), 256, 0, stream>>>(enc_w, wTed, 64, 6);
  transpose_w_f32_kernel<<<dim3(216), 256, 0, stream>>>(dec_w, wTdf, 32, 6);

  for (int c0 = 0; c0 < BATCH; c0 += BC) {
    const float* xb = x + (size_t)c0 * TB;

    // encoder (f64)
    enc0_f64_kernel<<<dim3(8, BC), 256, 0, stream>>>(
        xb, enc0_w1, enc0_b1, wT0d, enc0_b2, enc0_ws, enc0_bs, E0d);
    for (int i = 0; i < 3; ++i) {
      conv64_f64_kernel<false><<<dim3(8, BC), 256, 0, stream>>>(
          E0d, wTed + (2 * i) * 36864, enc_b + (2 * i) * 64, nullptr, E1d);
      conv64_f64_kernel<true><<<dim3(8, BC), 256, 0, stream>>>(
          E1d, wTed + (2 * i + 1) * 36864, enc_b + (2 * i + 1) * 64, E0d, E0d);
    }

    // vector-quantize (writes idx outputs directly)
    code_assign_kernel<64><<<dim3(2, BC), 256, 0, stream>>>(
        E0d, 0, means_s, qs, out + 2 * 524288 + (size_t)c0 * TB);
    code_assign_kernel<32><<<dim3(2, BC), 256, 0, stream>>>(
        E0d, 32, means_n, qn, out + 3 * 524288 + (size_t)c0 * TB);

    // decoders; final z for stream s -> Dz rows [0,BC), n -> rows [BC,2BC)
    float* destS = Dz;
    float* destN = Dz + (size_t)BC * 16384;
    {
      float* outs[3] = {T1, qs, destS};
      const float* zin = qs;
      for (int i = 0; i < 3; ++i) {
        conv32_f32_kernel<false><<<dim3(4, BC), 256, 0, stream>>>(
            zin, wTdf + (2 * i) * 9216, dec_b + (2 * i) * 32, nullptr, D0);
        conv32_f32_kernel<true><<<dim3(4, BC), 256, 0, stream>>>(
            D0, wTdf + (2 * i + 1) * 9216, dec_b + (2 * i + 1) * 32, zin,
            outs[i]);
        zin = outs[i];
      }
    }
    {
      float* outs[3] = {T1, qn, destN};
      const float* zin = qn;
      for (int i = 0; i < 3; ++i) {
        conv32_f32_kernel<false><<<dim3(4, BC), 256, 0, stream>>>(
            zin, wTdf + (2 * i) * 9216, dec_b + (2 * i) * 32, nullptr, D0);
        conv32_f32_kernel<true><<<dim3(4, BC), 256, 0, stream>>>(
            D0, wTdf + (2 * i + 1) * 9216, dec_b + (2 * i + 1) * 32, zin,
            outs[i]);
        zin = outs[i];
      }
    }

    // FC: split-K partials + reduce
    fc_partial_gemm<<<dim3(8, (2 * BC) / 64, 8), 256, 0, stream>>>(
        Dz, fc1_w, PB, 2 * BC);
    fc_reduce_tanh<<<dim3((2 * BC * 512) / 256), 256, 0, stream>>>(
        PB, fc1_b, out, 2 * BC, BC, c0);
  }
}